// Round 10
// baseline (402.752 us; speedup 1.0000x reference)
//
#include <hip/hip_runtime.h>

#define NN 32768
#define HH 128
#define GG 50
#define EE 524288

constexpr float GSTEP = 10.0f / 49.0f;
constexpr float GCOEF = -0.5f / (GSTEP * GSTEP);
constexpr float PI_OVER_CUT = 0.31415926535897931f;   // pi / 10
constexpr float LOG2F_ = 0.69314718055994531f;
constexpr float LOG2E_ = 1.4426950408889634f;
constexpr float RLOG2E_ = 0.69314718055994531f;
constexpr float GC2 = GCOEF * LOG2E_;                 // gaussian exp -> exp2

typedef __attribute__((ext_vector_type(8))) short bf16x8;
typedef __attribute__((ext_vector_type(4))) float f32x4;
typedef unsigned short ushort_t;

__device__ __forceinline__ float fast_exp2(float x) {
    float r; asm("v_exp_f32 %0, %1" : "=v"(r) : "v"(x)); return r;
}
__device__ __forceinline__ float fast_log2(float x) {
    float r; asm("v_log_f32 %0, %1" : "=v"(r) : "v"(x)); return r;
}
__device__ __forceinline__ float fexpf(float x) {      // e^x via v_exp_f32
    return fast_exp2(x * LOG2E_);
}
__device__ __forceinline__ float sspf(float x) {       // softplus(x) - log2
    const float p = fast_exp2(x * LOG2E_);
    const float r = RLOG2E_ * fast_log2(1.0f + p) - LOG2F_;
    return (x > 80.0f) ? (x - LOG2F_) : r;
}
__device__ __forceinline__ unsigned fenc(float f) {
    unsigned b = __float_as_uint(f);
    return (b & 0x80000000u) ? ~b : (b | 0x80000000u);
}
__device__ __forceinline__ float fdec(unsigned u) {
    unsigned b = (u & 0x80000000u) ? (u ^ 0x80000000u) : ~u;
    return __uint_as_float(b);
}
__device__ __forceinline__ int get_mask(const void* mp, int mode, int e) {
    if (mode) return ((const unsigned char*)mp)[e] != 0;
    return ((const int*)mp)[e] != 0;
}
__device__ __forceinline__ ushort_t f2bf(float f) {   // RNE f32 -> bf16
    unsigned u = __float_as_uint(f);
    return (ushort_t)((u + 0x7FFFu + ((u >> 16) & 1u)) >> 16);
}
__device__ __forceinline__ float bf2f(ushort_t s) { return __uint_as_float(((unsigned)s) << 16); }

// ---------------------------------------------------------------------------
__global__ void k_detect(const unsigned char* __restrict__ mb, int* __restrict__ flag) {
    __shared__ int any;
    if (threadIdx.x == 0) any = 0;
    __syncthreads();
    int local = 0;
    for (int i = threadIdx.x; i < 16384; i += blockDim.x)
        if ((i & 3) != 0 && mb[i]) local = 1;
    if (local) atomicOr(&any, 1);
    __syncthreads();
    if (threadIdx.x == 0) *flag = any;   // 1 => byte mode, 0 => int32 mode
}

// ---------------------------------------------------------------------------
// One-time: transpose all weights to bf16 [n][k] layouts (k zero-padded).
__global__ void k_prep_w(const float* __restrict__ filt_w1, const float* __restrict__ filt_w2,
                         const float* __restrict__ attn_w1, const float* __restrict__ lin1_w,
                         const float* __restrict__ lin2_w, const float* __restrict__ lin_w,
                         ushort_t* __restrict__ w1t, ushort_t* __restrict__ w1ct,
                         ushort_t* __restrict__ w2t, ushort_t* __restrict__ wut,
                         ushort_t* __restrict__ wvt, ushort_t* __restrict__ wxt,
                         ushort_t* __restrict__ l2t, ushort_t* __restrict__ lwt)
{
    const int t = blockIdx.x * 256 + threadIdx.x;
    if (t < 8192) {                          // w1t[n][g], g padded 50->64
        const int n = t >> 6, g = t & 63;
        w1t[t] = f2bf((g < GG) ? filt_w1[g * HH + n] : 0.0f);
    } else if (t < 16384) {                  // w1ct[n][g]
        const int i = t - 8192, n = i >> 6, g = i & 63;
        w1ct[i] = f2bf((g < GG) ? attn_w1[(size_t)(256 + g) * HH + n] : 0.0f);
    } else if (t < 32768) {                  // w2t[n][k]
        const int i = t - 16384, n = i >> 7, k = i & 127;
        w2t[i] = f2bf(filt_w2[k * HH + n]);
    } else if (t < 49152) {                  // wut[n][k] = attn_w1 rows 0..127
        const int i = t - 32768, n = i >> 7, k = i & 127;
        wut[i] = f2bf(attn_w1[(size_t)k * HH + n]);
    } else if (t < 65536) {                  // wvt[n][k] = attn_w1 rows 128..255
        const int i = t - 49152, n = i >> 7, k = i & 127;
        wvt[i] = f2bf(attn_w1[(size_t)(128 + k) * HH + n]);
    } else if (t < 81920) {                  // wxt[n][k] = lin1_w
        const int i = t - 65536, n = i >> 7, k = i & 127;
        wxt[i] = f2bf(lin1_w[(size_t)k * HH + n]);
    } else if (t < 98304) {                  // l2t[n][k] = lin2_w
        const int i = t - 81920, n = i >> 7, k = i & 127;
        l2t[i] = f2bf(lin2_w[(size_t)k * HH + n]);
    } else if (t < 114688) {                 // lwt[n][k] = lin_w
        const int i = t - 98304, n = i >> 7, k = i & 127;
        lwt[i] = f2bf(lin_w[(size_t)k * HH + n]);
    }
}

// ---------------------------------------------------------------------------
// MFMA node projections: out = bf16(h @ W) for W in {attn_u, attn_v, lin1}.
__global__ __launch_bounds__(256, 4) void k_node_proj(
    const float* __restrict__ h,
    const ushort_t* __restrict__ wut, const ushort_t* __restrict__ wvt,
    const ushort_t* __restrict__ wxt,
    ushort_t* __restrict__ ub, ushort_t* __restrict__ vb, ushort_t* __restrict__ xhb)
{
    __shared__ alignas(16) unsigned char smem[32768];
    unsigned char* HB = smem;          // bf16[64][128], swz ((row&7)<<4)
    unsigned char* WB = smem + 16384;  // bf16[64n][128k] half, swz ((n&7)<<4)

    const int tid = threadIdx.x;
    const int n0 = blockIdx.x * 64;
    const int mat = blockIdx.y;
    const ushort_t* __restrict__ wt = (mat == 0) ? wut : (mat == 1 ? wvt : wxt);
    ushort_t* __restrict__ out = (mat == 0) ? ub : (mat == 1 ? vb : xhb);

    for (int p = tid; p < 2048; p += 256) {        // stage HB (f32 -> bf16)
        const int row = p >> 5, c4 = p & 31;
        const float4 v = *(const float4*)(h + (size_t)(n0 + row) * HH + c4 * 4);
        uint2 pk = {(unsigned)f2bf(v.x) | ((unsigned)f2bf(v.y) << 16),
                    (unsigned)f2bf(v.z) | ((unsigned)f2bf(v.w) << 16)};
        const int lbyte = row * 256 + c4 * 8;
        *(uint2*)(HB + (lbyte ^ ((row & 7) << 4))) = pk;
    }
    for (int p = tid; p < 1024; p += 256) {        // stage WB half0
        const int byte = p * 16; const int nl = byte >> 8;
        *(float4*)(WB + (byte ^ ((nl & 7) << 4))) = *(const float4*)((const char*)wt + byte);
    }
    __syncthreads();

    const int lane = tid & 63, wv = tid >> 6, col0 = lane & 15, g4 = lane >> 4;
    const int m = wv * 16 + col0;
    f32x4 acc[8] = {};
#pragma unroll
    for (int hh2 = 0; hh2 < 2; hh2++) {
        if (hh2 == 1) {
            __syncthreads();
            for (int p = tid; p < 1024; p += 256) {
                const int byte = p * 16; const int nl = byte >> 8;
                *(float4*)(WB + (byte ^ ((nl & 7) << 4))) =
                    *(const float4*)((const char*)wt + 16384 + byte);
            }
            __syncthreads();
        }
#pragma unroll
        for (int kk = 0; kk < 4; kk++) {
            const int abyte = m * 256 + kk * 64 + g4 * 16;
            const bf16x8 af = *(const bf16x8*)(HB + (abyte ^ ((m & 7) << 4)));
#pragma unroll
            for (int q = 0; q < 4; q++) {
                const int l = q * 16 + col0;
                const int bbyte = l * 256 + kk * 64 + g4 * 16;
                const bf16x8 bf_ = *(const bf16x8*)(WB + (bbyte ^ ((l & 7) << 4)));
                acc[hh2 * 4 + q] = __builtin_amdgcn_mfma_f32_16x16x32_bf16(af, bf_, acc[hh2 * 4 + q], 0, 0, 0);
            }
        }
    }
#pragma unroll
    for (int f = 0; f < 8; f++) {
        const int col = (f >> 2) * 64 + (f & 3) * 16 + col0;
#pragma unroll
        for (int rg = 0; rg < 4; rg++) {
            const int row = wv * 16 + g4 * 4 + rg;
            out[(size_t)(n0 + row) * HH + col] = f2bf(acc[f][rg]);
        }
    }
}

// ---------------------------------------------------------------------------
// One pass over all edges: dest histogram + masked-edge compaction.
__global__ void k_compact(const int* __restrict__ ei, const void* __restrict__ maskp,
                          const int* __restrict__ flagp,
                          int* __restrict__ count, int* __restrict__ mcount,
                          uint2* __restrict__ mrec)
{
    const int e = blockIdx.x * 256 + threadIdx.x;
    if (e >= EE) return;
    const int r = ei[e], c = ei[EE + e];
    atomicAdd(&count[c], 1);
    const int mode = *flagp;
    if (get_mask(maskp, mode, e)) {
        const int pos = atomicAdd(mcount, 1);
        uint2 rec = {(unsigned)e, (unsigned)r | ((unsigned)c << 16)};
        mrec[pos] = rec;
    }
}

// ---------------------------------------------------------------------------
// Edge scores via MFMA over the compacted MASKED edge list only.
__global__ __launch_bounds__(256, 4) void k_edge_score(
    const float* __restrict__ pos, const uint2* __restrict__ mrec,
    const int* __restrict__ mcount,
    const ushort_t* __restrict__ ub, const ushort_t* __restrict__ vb,
    const ushort_t* __restrict__ w1ct, const float* __restrict__ attn_b1,
    const float* __restrict__ attn_w2, const float* __restrict__ attn_b2,
    float* __restrict__ score, unsigned* __restrict__ menc)
{
    __shared__ alignas(16) unsigned char EA[8192];     // bf16[64e][64k], swz ((e&7)<<4)
    __shared__ alignas(16) unsigned char WC[16384];    // bf16[128n][64k], swz ((n&7)<<4)
    __shared__ float dsh[64];
    __shared__ int rsh[64], csh[64], esh[64];
    __shared__ int Em_s;

    const int tid  = threadIdx.x;
    if (tid == 0) Em_s = *mcount;
    __syncthreads();
    const int Em = Em_s;
    const int base = blockIdx.x * 64;
    if (base >= Em) return;

    const int lane = tid & 63;
    const int wv   = tid >> 6;
    const int col0 = lane & 15;
    const int g4   = lane >> 4;

    if (tid < 64) {
        const int slot = base + tid;
        int e = -1, r = 0, c = 0;
        if (slot < Em) {
            const uint2 rec = mrec[slot];
            e = (int)rec.x;
            r = (int)(rec.y & 0xFFFFu);
            c = (int)(rec.y >> 16);
        }
        esh[tid] = e; rsh[tid] = r; csh[tid] = c;
        const float dx = pos[r * 3 + 0] - pos[c * 3 + 0];
        const float dy = pos[r * 3 + 1] - pos[c * 3 + 1];
        const float dz = pos[r * 3 + 2] - pos[c * 3 + 2];
        dsh[tid] = sqrtf(dx * dx + dy * dy + dz * dz);
    }
    for (int p = tid; p < 1024; p += 256) {            // stage WC: 16KB
        const int byte = p * 16;
        const int n = byte >> 7;
        *(float4*)(WC + (byte ^ ((n & 7) << 4))) = *(const float4*)((const char*)w1ct + byte);
    }
    __syncthreads();

    // u/v register prefetch (hidden under EA fill + GEMM)
    int rrv[4], ccv[4];
#pragma unroll
    for (int rg = 0; rg < 4; rg++) {
        const int e = wv * 16 + g4 * 4 + rg;
        rrv[rg] = rsh[e];
        ccv[rg] = csh[e];
    }
    ushort_t ur[4][8], vr[4][8];
#pragma unroll
    for (int rg = 0; rg < 4; rg++)
#pragma unroll
        for (int n = 0; n < 8; n++) {
            ur[rg][n] = ub[(size_t)rrv[rg] * HH + n * 16 + col0];
            vr[rg][n] = vb[(size_t)ccv[rg] * HH + n * 16 + col0];
        }

    // EA fill (bf16 gaussians)
    {
        const int e = tid & 63, jg = tid >> 6;
        const float d = dsh[e];
        for (int jj = jg; jj < 8; jj += 4) {
            bf16x8 pk;
#pragma unroll
            for (int b = 0; b < 8; b++) {
                const int g = jj * 8 + b;
                float val = 0.0f;
                if (g < GG) { const float t = d - g * GSTEP; val = fast_exp2(GC2 * t * t); }
                pk[b] = (short)f2bf(val);
            }
            const int byte = e * 128 + jj * 16;
            *(bf16x8*)(EA + (byte ^ ((e & 7) << 4))) = pk;
        }
    }
    float b1v[8], w2v[8];
#pragma unroll
    for (int n = 0; n < 8; n++) {
        b1v[n] = attn_b1[n * 16 + col0];
        w2v[n] = attn_w2[n * 16 + col0];
    }
    __syncthreads();

    const int m = wv * 16 + col0;
    f32x4 acc[8] = {};
#pragma unroll
    for (int kk = 0; kk < 2; kk++) {
        const int abyte = m * 128 + kk * 64 + g4 * 16;
        const bf16x8 af = *(const bf16x8*)(EA + (abyte ^ ((m & 7) << 4)));
#pragma unroll
        for (int n = 0; n < 8; n++) {
            const int l = n * 16 + col0;
            const int bbyte = l * 128 + kk * 64 + g4 * 16;
            const bf16x8 bf_ = *(const bf16x8*)(WC + (bbyte ^ ((l & 7) << 4)));
            acc[n] = __builtin_amdgcn_mfma_f32_16x16x32_bf16(af, bf_, acc[n], 0, 0, 0);
        }
    }

    float pe[4] = {0.0f, 0.0f, 0.0f, 0.0f};
#pragma unroll
    for (int n = 0; n < 8; n++) {
#pragma unroll
        for (int rg = 0; rg < 4; rg++) {
            float z = acc[n][rg] + bf2f(ur[rg][n]) + bf2f(vr[rg][n]) + b1v[n];
            z = fmaxf(z, 0.0f);
            pe[rg] += z * w2v[n];
        }
    }
#pragma unroll
    for (int mask = 1; mask <= 8; mask <<= 1) {
#pragma unroll
        for (int rg = 0; rg < 4; rg++)
            pe[rg] += __shfl_xor(pe[rg], mask, 64);
    }
    if (col0 == 0) {
        const float b2 = attn_b2[0];
#pragma unroll
        for (int rg = 0; rg < 4; rg++) {
            const int le = wv * 16 + g4 * 4 + rg;
            const int e = esh[le];
            if (e >= 0) {
                const float s = pe[rg] + b2;
                score[e] = s;
                atomicMax(&menc[rsh[le]], fenc(s));
            }
        }
    }
}

// ---------------------------------------------------------------------------
__global__ void k_ssum(const uint2* __restrict__ mrec, const int* __restrict__ mcount,
                       const float* __restrict__ score, const unsigned* __restrict__ menc,
                       float* __restrict__ ssum)
{
    const int slot = blockIdx.x * 256 + threadIdx.x;
    if (slot >= *mcount) return;
    const uint2 rec = mrec[slot];
    const int e = (int)rec.x;
    const int r = (int)(rec.y & 0xFFFFu);
    atomicAdd(&ssum[r], fexpf(score[e] - fdec(menc[r])));
}

// ---------------------------------------------------------------------------
__global__ __launch_bounds__(512) void k_scan(const int* __restrict__ count,
                                              int* __restrict__ cursor)
{
    __shared__ int s[512];
    const int t = threadIdx.x;
    const int base_i = t * 64;
    int sum = 0;
    for (int i = 0; i < 64; i++) sum += count[base_i + i];
    s[t] = sum;
    __syncthreads();
    for (int off = 1; off < 512; off <<= 1) {
        int v = (t >= off) ? s[t - off] : 0;
        __syncthreads();
        s[t] += v;
        __syncthreads();
    }
    int run = s[t] - sum;   // exclusive prefix
    for (int i = 0; i < 64; i++) {
        cursor[base_i + i] = run;
        run += count[base_i + i];
    }
}

// ---------------------------------------------------------------------------
// Scatter edges into dest-sorted order, materializing packed records
// erec[pos] = {d, dec, r|(c<<16), 0}. ssum/menc final before this runs.
__global__ void k_scatter(const int* __restrict__ ei, const void* __restrict__ maskp,
                          const int* __restrict__ flagp, const float* __restrict__ pos,
                          const float* __restrict__ score,
                          const unsigned* __restrict__ menc, const float* __restrict__ ssum,
                          int* __restrict__ cursor, uint4* __restrict__ erec)
{
    const int e = blockIdx.x * 256 + threadIdx.x;
    if (e >= EE) return;
    const int r = ei[e], c = ei[EE + e];
    const int p = atomicAdd(&cursor[c], 1);
    const float dx = pos[r * 3 + 0] - pos[c * 3 + 0];
    const float dy = pos[r * 3 + 1] - pos[c * 3 + 1];
    const float dz = pos[r * 3 + 2] - pos[c * 3 + 2];
    const float d = sqrtf(dx * dx + dy * dy + dz * dz);
    float dec = 1.0f;
    const int mode = *flagp;
    if (get_mask(maskp, mode, e)) {
        const float m = fdec(menc[r]);
        dec = fexpf(score[e] - m) / (ssum[r] + 1e-16f);
    }
    uint4 rec = {__float_as_uint(d), __float_as_uint(dec),
                 (unsigned)r | ((unsigned)c << 16), 0u};
    erec[p] = rec;
}

// ---------------------------------------------------------------------------
// MFMA filter MLP on dest-sorted edge records + LDS segmented reduction.
__global__ __launch_bounds__(256, 4) void k_filter_mfma(
    const uint4* __restrict__ erec,
    const ushort_t* __restrict__ w1t, const float* __restrict__ filt_b1,
    const ushort_t* __restrict__ w2t, const float* __restrict__ filt_b2,
    const ushort_t* __restrict__ xhb, float* __restrict__ agg)
{
    __shared__ alignas(16) unsigned char smem[32768];
    unsigned char* EA = smem;
    unsigned char* W1 = smem + 8192;
    unsigned char* T1 = smem + 16384;
    unsigned char* WB = smem;
    float* msgb = (float*)smem;

    __shared__ float dsh[64], decsh[64], Csh[64];
    __shared__ int rsh[64], csh[64];
    __shared__ int shflags;

    const int tid  = threadIdx.x;
    const int e0   = blockIdx.x * 64;
    const int lane = tid & 63;
    const int wv   = tid >> 6;
    const int col0 = lane & 15;
    const int g4   = lane >> 4;

    // ---- phase A: coalesced record load + stage W1 half0 ----
    if (tid < 64) {
        const uint4 rec = erec[e0 + tid];
        const float d = __uint_as_float(rec.x);
        dsh[tid] = d;
        decsh[tid] = __uint_as_float(rec.y);
        rsh[tid] = (int)(rec.z & 0xFFFFu);
        csh[tid] = (int)(rec.z >> 16);
        Csh[tid] = 0.5f * (cosf(d * PI_OVER_CUT) + 1.0f);
    }
    if (tid == 64) {
        const unsigned cf = erec[e0].z >> 16;
        const unsigned cl = erec[e0 + 63].z >> 16;
        int f = 0;
        if (e0 > 0 && (erec[e0 - 1].z >> 16) == cf) f |= 1;
        if (e0 + 64 < EE && (erec[e0 + 64].z >> 16) == cl) f |= 2;
        shflags = f;
    }
    for (int p = tid; p < 512; p += 256) {       // W1 half0: 8KB
        const int byte = p * 16;
        const int n = byte >> 7;
        *(float4*)(W1 + (byte ^ ((n & 7) << 4))) = *(const float4*)((const char*)w1t + byte);
    }
    __syncthreads();

    // ---- phase B: EA fill + xh register prefetch ----
    {
        const int e = tid & 63, jg = tid >> 6;
        const float d = dsh[e], dec = decsh[e];
        for (int jj = jg; jj < 8; jj += 4) {
            bf16x8 pk;
#pragma unroll
            for (int b = 0; b < 8; b++) {
                const int g = jj * 8 + b;
                float val = 0.0f;
                if (g < GG) { const float t = d - g * GSTEP; val = fast_exp2(GC2 * t * t) * dec; }
                pk[b] = (short)f2bf(val);
            }
            const int byte = e * 128 + jj * 16;
            *(bf16x8*)(EA + (byte ^ ((e & 7) << 4))) = pk;
        }
    }
    int rr[4]; float CC[4];
#pragma unroll
    for (int rg = 0; rg < 4; rg++) {
        const int e = wv * 16 + g4 * 4 + rg;
        rr[rg] = rsh[e];
        CC[rg] = Csh[e];
    }
    ushort_t xr[4][8];                           // issued here, used in epilogue2
#pragma unroll
    for (int rg = 0; rg < 4; rg++)
#pragma unroll
        for (int n = 0; n < 8; n++)
            xr[rg][n] = xhb[(size_t)rr[rg] * HH + n * 16 + col0];
    float b1v[8], b2v[8];
#pragma unroll
    for (int n = 0; n < 8; n++) {
        b1v[n] = filt_b1[n * 16 + col0];
        b2v[n] = filt_b2[n * 16 + col0];
    }
    __syncthreads();

    // ---- GEMM1: T1 = ssp(ea @ w1 + b1), W1 staged in two 8KB halves ----
    const int m = wv * 16 + col0;
    f32x4 acc[8] = {};
#pragma unroll
    for (int h = 0; h < 2; h++) {
        if (h == 1) {
            __syncthreads();
            for (int p = tid; p < 512; p += 256) {
                const int byte = p * 16;
                const int n = byte >> 7;
                *(float4*)(W1 + (byte ^ ((n & 7) << 4))) =
                    *(const float4*)((const char*)w1t + 8192 + byte);
            }
            __syncthreads();
        }
#pragma unroll
        for (int kk = 0; kk < 2; kk++) {
            const int abyte = m * 128 + kk * 64 + g4 * 16;
            const bf16x8 af = *(const bf16x8*)(EA + (abyte ^ ((m & 7) << 4)));
#pragma unroll
            for (int q = 0; q < 4; q++) {
                const int l = q * 16 + col0;
                const int bbyte = l * 128 + kk * 64 + g4 * 16;
                const bf16x8 bf_ = *(const bf16x8*)(W1 + (bbyte ^ ((l & 7) << 4)));
                acc[h * 4 + q] = __builtin_amdgcn_mfma_f32_16x16x32_bf16(af, bf_, acc[h * 4 + q], 0, 0, 0);
            }
        }
    }
    // epilogue1 -> T1 (bf16)
#pragma unroll
    for (int n = 0; n < 8; n++) {
#pragma unroll
        for (int rg = 0; rg < 4; rg++) {
            const int row = wv * 16 + g4 * 4 + rg;
            const float tv = sspf(acc[n][rg] + b1v[n]);
            const int lbyte = row * 256 + (n * 16 + col0) * 2;
            *(ushort_t*)(T1 + (lbyte ^ ((row & 7) << 4))) = f2bf(tv);
        }
    }
    __syncthreads();

    // ---- GEMM2: W = t1 @ w2 + b2, WB staged in two 16KB halves over EA/W1 ----
    f32x4 acc2[8] = {};
#pragma unroll
    for (int h = 0; h < 2; h++) {
        for (int p = tid; p < 1024; p += 256) {
            const int byte = p * 16;
            const int nl = byte >> 8;
            *(float4*)(WB + (byte ^ ((nl & 7) << 4))) =
                *(const float4*)((const char*)w2t + h * 16384 + byte);
        }
        __syncthreads();
#pragma unroll
        for (int kk = 0; kk < 4; kk++) {
            const int abyte = m * 256 + kk * 64 + g4 * 16;
            const bf16x8 af = *(const bf16x8*)(T1 + (abyte ^ ((m & 7) << 4)));
#pragma unroll
            for (int q = 0; q < 4; q++) {
                const int l = q * 16 + col0;
                const int bbyte = l * 256 + kk * 64 + g4 * 16;
                const bf16x8 bf_ = *(const bf16x8*)(WB + (bbyte ^ ((l & 7) << 4)));
                acc2[h * 4 + q] = __builtin_amdgcn_mfma_f32_16x16x32_bf16(af, bf_, acc2[h * 4 + q], 0, 0, 0);
            }
        }
        __syncthreads();
    }

    // ---- epilogue2: msg = xh[r] * (W+b2) * C -> msgb (skewed, overlay) ----
#pragma unroll
    for (int n = 0; n < 8; n++) {
        const int col = n * 16 + col0;
#pragma unroll
        for (int rg = 0; rg < 4; rg++) {
            const int e = wv * 16 + g4 * 4 + rg;
            const float Wv = (acc2[n][rg] + b2v[n]) * CC[rg];
            const float xv = __uint_as_float(((unsigned)xr[rg][n]) << 16);
            msgb[e * 128 + ((col + 8 * g4) & 127)] = xv * Wv;
        }
    }
    __syncthreads();

    // ---- segmented reduction: 2 halves x 32 edges, all 256 threads ----
    {
        const int q = tid >> 7;          // 0 or 1
        const int j = tid & 127;
        const int base = q * 32;
        const int fl = shflags;
        const int cfirst = csh[base], clast = csh[base + 31];
        const int f1 = (q == 0) ? (fl & 1) : (csh[base - 1] == cfirst);
        const int f2 = (q == 1) ? (fl & 2) : (csh[base + 32] == clast);
        float a = msgb[base * 128 + ((j + 8 * ((base >> 2) & 3)) & 127)];
        int cur = cfirst;
        for (int e = base + 1; e < base + 32; e++) {
            const int de = csh[e];
            if (de != cur) {
                if ((cur == cfirst && f1) || (cur == clast && f2))
                    atomicAdd(&agg[(size_t)cur * HH + j], a);
                else
                    agg[(size_t)cur * HH + j] = a;
                a = 0.0f;
                cur = de;
            }
            a += msgb[e * 128 + ((j + 8 * ((e >> 2) & 3)) & 127)];
        }
        if ((cur == cfirst && f1) || (cur == clast && f2))
            atomicAdd(&agg[(size_t)cur * HH + j], a);
        else
            agg[(size_t)cur * HH + j] = a;
    }
}

// ---------------------------------------------------------------------------
// MFMA final: out = ssp(agg @ lin2 + b2) @ lin + b.
__global__ __launch_bounds__(256, 4) void k_final(
    const float* __restrict__ agg, const ushort_t* __restrict__ l2t,
    const float* __restrict__ lin2_b, const ushort_t* __restrict__ lwt,
    const float* __restrict__ lin_b, float* __restrict__ out)
{
    __shared__ alignas(16) unsigned char smem[32768];
    unsigned char* AB = smem;          // bf16[64][128] swz; later T1
    unsigned char* WB = smem + 16384;
    unsigned char* T1 = smem;

    const int tid = threadIdx.x;
    const int n0 = blockIdx.x * 64;

    for (int p = tid; p < 2048; p += 256) {        // stage AB (f32 -> bf16)
        const int row = p >> 5, c4 = p & 31;
        const float4 v = *(const float4*)(agg + (size_t)(n0 + row) * HH + c4 * 4);
        uint2 pk = {(unsigned)f2bf(v.x) | ((unsigned)f2bf(v.y) << 16),
                    (unsigned)f2bf(v.z) | ((unsigned)f2bf(v.w) << 16)};
        const int lbyte = row * 256 + c4 * 8;
        *(uint2*)(AB + (lbyte ^ ((row & 7) << 4))) = pk;
    }
    for (int p = tid; p < 1024; p += 256) {        // stage WB: l2t half0
        const int byte = p * 16; const int nl = byte >> 8;
        *(float4*)(WB + (byte ^ ((nl & 7) << 4))) = *(const float4*)((const char*)l2t + byte);
    }
    __syncthreads();

    const int lane = tid & 63, wv = tid >> 6, col0 = lane & 15, g4 = lane >> 4;
    const int m = wv * 16 + col0;
    float b1v[8], b2v[8];
#pragma unroll
    for (int f = 0; f < 8; f++) {
        const int colf = (f >> 2) * 64 + (f & 3) * 16 + col0;
        b1v[f] = lin2_b[colf];
        b2v[f] = lin_b[colf];
    }

    f32x4 acc[8] = {};
#pragma unroll
    for (int h = 0; h < 2; h++) {
        if (h == 1) {
            __syncthreads();
            for (int p = tid; p < 1024; p += 256) {
                const int byte = p * 16; const int nl = byte >> 8;
                *(float4*)(WB + (byte ^ ((nl & 7) << 4))) =
                    *(const float4*)((const char*)l2t + 16384 + byte);
            }
            __syncthreads();
        }
#pragma unroll
        for (int kk = 0; kk < 4; kk++) {
            const int abyte = m * 256 + kk * 64 + g4 * 16;
            const bf16x8 af = *(const bf16x8*)(AB + (abyte ^ ((m & 7) << 4)));
#pragma unroll
            for (int q = 0; q < 4; q++) {
                const int l = q * 16 + col0;
                const int bbyte = l * 256 + kk * 64 + g4 * 16;
                const bf16x8 bf_ = *(const bf16x8*)(WB + (bbyte ^ ((l & 7) << 4)));
                acc[h * 4 + q] = __builtin_amdgcn_mfma_f32_16x16x32_bf16(af, bf_, acc[h * 4 + q], 0, 0, 0);
            }
        }
    }
    __syncthreads();   // all GEMM1 reads done; AB may be overlaid by T1

    // T2 = ssp(acc + b1) -> T1 (bf16); stage WB: lwt half0 in parallel
#pragma unroll
    for (int f = 0; f < 8; f++) {
        const int colf = (f >> 2) * 64 + (f & 3) * 16 + col0;
#pragma unroll
        for (int rg = 0; rg < 4; rg++) {
            const int row = wv * 16 + g4 * 4 + rg;
            const float tv = sspf(acc[f][rg] + b1v[f]);
            const int lbyte = row * 256 + colf * 2;
            *(ushort_t*)(T1 + (lbyte ^ ((row & 7) << 4))) = f2bf(tv);
        }
    }
    for (int p = tid; p < 1024; p += 256) {
        const int byte = p * 16; const int nl = byte >> 8;
        *(float4*)(WB + (byte ^ ((nl & 7) << 4))) = *(const float4*)((const char*)lwt + byte);
    }
    __syncthreads();

    f32x4 acc2[8] = {};
#pragma unroll
    for (int h = 0; h < 2; h++) {
        if (h == 1) {
            __syncthreads();
            for (int p = tid; p < 1024; p += 256) {
                const int byte = p * 16; const int nl = byte >> 8;
                *(float4*)(WB + (byte ^ ((nl & 7) << 4))) =
                    *(const float4*)((const char*)lwt + 16384 + byte);
            }
            __syncthreads();
        }
#pragma unroll
        for (int kk = 0; kk < 4; kk++) {
            const int abyte = m * 256 + kk * 64 + g4 * 16;
            const bf16x8 af = *(const bf16x8*)(T1 + (abyte ^ ((m & 7) << 4)));
#pragma unroll
            for (int q = 0; q < 4; q++) {
                const int l = q * 16 + col0;
                const int bbyte = l * 256 + kk * 64 + g4 * 16;
                const bf16x8 bf_ = *(const bf16x8*)(WB + (bbyte ^ ((l & 7) << 4)));
                acc2[h * 4 + q] = __builtin_amdgcn_mfma_f32_16x16x32_bf16(af, bf_, acc2[h * 4 + q], 0, 0, 0);
            }
        }
    }
#pragma unroll
    for (int f = 0; f < 8; f++) {
        const int colf = (f >> 2) * 64 + (f & 3) * 16 + col0;
#pragma unroll
        for (int rg = 0; rg < 4; rg++) {
            const int row = wv * 16 + g4 * 4 + rg;
            out[(size_t)(n0 + row) * HH + colf] = acc2[f][rg] + b2v[f];
        }
    }
}

// ---------------------------------------------------------------------------
__global__ void k_copy_pos(const float* __restrict__ pos, float* __restrict__ out) {
    const int i = blockIdx.x * 256 + threadIdx.x;
    if (i < NN * 3) out[i] = pos[i];
}

// ---------------------------------------------------------------------------
extern "C" void kernel_launch(void* const* d_in, const int* in_sizes, int n_in,
                              void* d_out, int out_size, void* d_ws, size_t ws_size,
                              hipStream_t stream)
{
    const float* h       = (const float*)d_in[0];
    const float* pos     = (const float*)d_in[1];
    const int*   ei      = (const int*)d_in[2];
    const void*  maskp   = d_in[3];
    const float* attn_w1 = (const float*)d_in[4];
    const float* attn_b1 = (const float*)d_in[5];
    const float* attn_w2 = (const float*)d_in[6];
    const float* attn_b2 = (const float*)d_in[7];
    const float* filt_w1 = (const float*)d_in[8];
    const float* filt_b1 = (const float*)d_in[9];
    const float* filt_w2 = (const float*)d_in[10];
    const float* filt_b2 = (const float*)d_in[11];
    const float* lin1_w  = (const float*)d_in[12];
    const float* lin2_w  = (const float*)d_in[13];
    const float* lin2_b  = (const float*)d_in[14];
    const float* lin_w   = (const float*)d_in[15];
    const float* lin_b   = (const float*)d_in[16];

    char* p = (char*)d_ws;
    auto alloc = [&](size_t bytes) { char* r = p; p += (bytes + 255) & ~(size_t)255; return r; };

    ushort_t* ub    = (ushort_t*)alloc((size_t)NN * HH * 2);
    ushort_t* vb    = (ushort_t*)alloc((size_t)NN * HH * 2);
    ushort_t* xhb   = (ushort_t*)alloc((size_t)NN * HH * 2);
    float*    score = (float*)alloc((size_t)EE * 4);
    unsigned* menc  = (unsigned*)alloc((size_t)NN * 4);   // menc/ssum/count/mcount
    float*    ssum  = (float*)alloc((size_t)NN * 4);      // contiguous zero block
    int*      count = (int*)alloc((size_t)NN * 4);
    int*      mcount= (int*)alloc(4);
    int*      cursor= (int*)alloc((size_t)NN * 4);
    float*    agg   = (float*)alloc((size_t)NN * HH * 4);
    int*      flag  = (int*)alloc(4);
    uint2*    mrec  = (uint2*)alloc((size_t)EE * 8);
    uint4*    erec  = (uint4*)alloc((size_t)EE * 16);
    ushort_t* w1t   = (ushort_t*)alloc((size_t)128 * 64 * 2);
    ushort_t* w1ct  = (ushort_t*)alloc((size_t)128 * 64 * 2);
    ushort_t* w2t   = (ushort_t*)alloc((size_t)128 * 128 * 2);
    ushort_t* wut   = (ushort_t*)alloc((size_t)128 * 128 * 2);
    ushort_t* wvt   = (ushort_t*)alloc((size_t)128 * 128 * 2);
    ushort_t* wxt   = (ushort_t*)alloc((size_t)128 * 128 * 2);
    ushort_t* l2t   = (ushort_t*)alloc((size_t)128 * 128 * 2);
    ushort_t* lwt   = (ushort_t*)alloc((size_t)128 * 128 * 2);

    float* out_h   = (float*)d_out;
    float* out_pos = out_h + (size_t)NN * HH;

    hipMemsetAsync(menc, 0, (size_t)3 * NN * 4 + 256, stream);  // menc+ssum+count+mcount

    k_detect<<<1, 256, 0, stream>>>((const unsigned char*)maskp, flag);
    k_prep_w<<<448, 256, 0, stream>>>(filt_w1, filt_w2, attn_w1, lin1_w, lin2_w, lin_w,
                                      w1t, w1ct, w2t, wut, wvt, wxt, l2t, lwt);
    k_node_proj<<<dim3(NN / 64, 3), 256, 0, stream>>>(h, wut, wvt, wxt, ub, vb, xhb);
    k_compact<<<EE / 256, 256, 0, stream>>>(ei, maskp, flag, count, mcount, mrec);
    k_edge_score<<<EE / 64, 256, 0, stream>>>(pos, mrec, mcount, ub, vb,
                                              w1ct, attn_b1, attn_w2, attn_b2,
                                              score, menc);
    k_ssum<<<EE / 256, 256, 0, stream>>>(mrec, mcount, score, menc, ssum);
    k_scan<<<1, 512, 0, stream>>>(count, cursor);
    k_scatter<<<EE / 256, 256, 0, stream>>>(ei, maskp, flag, pos, score, menc, ssum,
                                            cursor, erec);

    hipMemsetAsync(agg, 0, (size_t)NN * HH * sizeof(float), stream);
    k_filter_mfma<<<EE / 64, 256, 0, stream>>>(erec, w1t, filt_b1, w2t, filt_b2, xhb, agg);

    k_final<<<NN / 64, 256, 0, stream>>>(agg, l2t, lin2_b, lwt, lin_b, out_h);
    k_copy_pos<<<(NN * 3 + 255) / 256, 256, 0, stream>>>(pos, out_pos);
}

// Round 11
// 313.937 us; speedup vs baseline: 1.2829x; 1.2829x over previous
//
#include <hip/hip_runtime.h>

#define NN 32768
#define HH 128
#define GG 50
#define EE 524288

constexpr float GSTEP = 10.0f / 49.0f;
constexpr float GCOEF = -0.5f / (GSTEP * GSTEP);
constexpr float PI_OVER_CUT = 0.31415926535897931f;   // pi / 10
constexpr float LOG2F_ = 0.69314718055994531f;
constexpr float LOG2E_ = 1.4426950408889634f;
constexpr float RLOG2E_ = 0.69314718055994531f;
constexpr float GC2 = GCOEF * LOG2E_;                 // gaussian exp -> exp2

typedef __attribute__((ext_vector_type(8))) short bf16x8;
typedef __attribute__((ext_vector_type(4))) float f32x4;
typedef unsigned short ushort_t;

__device__ __forceinline__ float fast_exp2(float x) {
    float r; asm("v_exp_f32 %0, %1" : "=v"(r) : "v"(x)); return r;
}
__device__ __forceinline__ float fast_log2(float x) {
    float r; asm("v_log_f32 %0, %1" : "=v"(r) : "v"(x)); return r;
}
__device__ __forceinline__ float fexpf(float x) {      // e^x via v_exp_f32
    return fast_exp2(x * LOG2E_);
}
__device__ __forceinline__ float sspf(float x) {       // softplus(x) - log2
    const float p = fast_exp2(x * LOG2E_);
    const float r = RLOG2E_ * fast_log2(1.0f + p) - LOG2F_;
    return (x > 80.0f) ? (x - LOG2F_) : r;
}
__device__ __forceinline__ unsigned fenc(float f) {
    unsigned b = __float_as_uint(f);
    return (b & 0x80000000u) ? ~b : (b | 0x80000000u);
}
__device__ __forceinline__ float fdec(unsigned u) {
    unsigned b = (u & 0x80000000u) ? (u ^ 0x80000000u) : ~u;
    return __uint_as_float(b);
}
__device__ __forceinline__ int get_mask(const void* mp, int mode, int e) {
    if (mode) return ((const unsigned char*)mp)[e] != 0;
    return ((const int*)mp)[e] != 0;
}
__device__ __forceinline__ ushort_t f2bf(float f) {   // RNE f32 -> bf16
    unsigned u = __float_as_uint(f);
    return (ushort_t)((u + 0x7FFFu + ((u >> 16) & 1u)) >> 16);
}
__device__ __forceinline__ float bf2f(ushort_t s) { return __uint_as_float(((unsigned)s) << 16); }

// ---------------------------------------------------------------------------
__global__ void k_detect(const unsigned char* __restrict__ mb, int* __restrict__ flag) {
    __shared__ int any;
    if (threadIdx.x == 0) any = 0;
    __syncthreads();
    int local = 0;
    for (int i = threadIdx.x; i < 16384; i += blockDim.x)
        if ((i & 3) != 0 && mb[i]) local = 1;
    if (local) atomicOr(&any, 1);
    __syncthreads();
    if (threadIdx.x == 0) *flag = any;   // 1 => byte mode, 0 => int32 mode
}

// ---------------------------------------------------------------------------
// One-time: transpose all weights to bf16 [n][k] layouts (k zero-padded).
__global__ void k_prep_w(const float* __restrict__ filt_w1, const float* __restrict__ filt_w2,
                         const float* __restrict__ attn_w1, const float* __restrict__ lin1_w,
                         const float* __restrict__ lin2_w, const float* __restrict__ lin_w,
                         ushort_t* __restrict__ w1t, ushort_t* __restrict__ w1ct,
                         ushort_t* __restrict__ w2t, ushort_t* __restrict__ wut,
                         ushort_t* __restrict__ wvt, ushort_t* __restrict__ wxt,
                         ushort_t* __restrict__ l2t, ushort_t* __restrict__ lwt)
{
    const int t = blockIdx.x * 256 + threadIdx.x;
    if (t < 8192) {                          // w1t[n][g], g padded 50->64
        const int n = t >> 6, g = t & 63;
        w1t[t] = f2bf((g < GG) ? filt_w1[g * HH + n] : 0.0f);
    } else if (t < 16384) {                  // w1ct[n][g]
        const int i = t - 8192, n = i >> 6, g = i & 63;
        w1ct[i] = f2bf((g < GG) ? attn_w1[(size_t)(256 + g) * HH + n] : 0.0f);
    } else if (t < 32768) {                  // w2t[n][k]
        const int i = t - 16384, n = i >> 7, k = i & 127;
        w2t[i] = f2bf(filt_w2[k * HH + n]);
    } else if (t < 49152) {                  // wut[n][k] = attn_w1 rows 0..127
        const int i = t - 32768, n = i >> 7, k = i & 127;
        wut[i] = f2bf(attn_w1[(size_t)k * HH + n]);
    } else if (t < 65536) {                  // wvt[n][k] = attn_w1 rows 128..255
        const int i = t - 49152, n = i >> 7, k = i & 127;
        wvt[i] = f2bf(attn_w1[(size_t)(128 + k) * HH + n]);
    } else if (t < 81920) {                  // wxt[n][k] = lin1_w
        const int i = t - 65536, n = i >> 7, k = i & 127;
        wxt[i] = f2bf(lin1_w[(size_t)k * HH + n]);
    } else if (t < 98304) {                  // l2t[n][k] = lin2_w
        const int i = t - 81920, n = i >> 7, k = i & 127;
        l2t[i] = f2bf(lin2_w[(size_t)k * HH + n]);
    } else if (t < 114688) {                 // lwt[n][k] = lin_w
        const int i = t - 98304, n = i >> 7, k = i & 127;
        lwt[i] = f2bf(lin_w[(size_t)k * HH + n]);
    }
}

// ---------------------------------------------------------------------------
// MFMA node projections: out = bf16(h @ W) for W in {attn_u, attn_v, lin1}.
__global__ __launch_bounds__(256, 4) void k_node_proj(
    const float* __restrict__ h,
    const ushort_t* __restrict__ wut, const ushort_t* __restrict__ wvt,
    const ushort_t* __restrict__ wxt,
    ushort_t* __restrict__ ub, ushort_t* __restrict__ vb, ushort_t* __restrict__ xhb)
{
    __shared__ alignas(16) unsigned char smem[32768];
    unsigned char* HB = smem;          // bf16[64][128], swz ((row&7)<<4)
    unsigned char* WB = smem + 16384;  // bf16[64n][128k] half, swz ((n&7)<<4)

    const int tid = threadIdx.x;
    const int n0 = blockIdx.x * 64;
    const int mat = blockIdx.y;
    const ushort_t* __restrict__ wt = (mat == 0) ? wut : (mat == 1 ? wvt : wxt);
    ushort_t* __restrict__ out = (mat == 0) ? ub : (mat == 1 ? vb : xhb);

    for (int p = tid; p < 2048; p += 256) {        // stage HB (f32 -> bf16)
        const int row = p >> 5, c4 = p & 31;
        const float4 v = *(const float4*)(h + (size_t)(n0 + row) * HH + c4 * 4);
        uint2 pk = {(unsigned)f2bf(v.x) | ((unsigned)f2bf(v.y) << 16),
                    (unsigned)f2bf(v.z) | ((unsigned)f2bf(v.w) << 16)};
        const int lbyte = row * 256 + c4 * 8;
        *(uint2*)(HB + (lbyte ^ ((row & 7) << 4))) = pk;
    }
    for (int p = tid; p < 1024; p += 256) {        // stage WB half0
        const int byte = p * 16; const int nl = byte >> 8;
        *(float4*)(WB + (byte ^ ((nl & 7) << 4))) = *(const float4*)((const char*)wt + byte);
    }
    __syncthreads();

    const int lane = tid & 63, wv = tid >> 6, col0 = lane & 15, g4 = lane >> 4;
    const int m = wv * 16 + col0;
    f32x4 acc[8] = {};
#pragma unroll
    for (int hh2 = 0; hh2 < 2; hh2++) {
        if (hh2 == 1) {
            __syncthreads();
            for (int p = tid; p < 1024; p += 256) {
                const int byte = p * 16; const int nl = byte >> 8;
                *(float4*)(WB + (byte ^ ((nl & 7) << 4))) =
                    *(const float4*)((const char*)wt + 16384 + byte);
            }
            __syncthreads();
        }
#pragma unroll
        for (int kk = 0; kk < 4; kk++) {
            const int abyte = m * 256 + kk * 64 + g4 * 16;
            const bf16x8 af = *(const bf16x8*)(HB + (abyte ^ ((m & 7) << 4)));
#pragma unroll
            for (int q = 0; q < 4; q++) {
                const int l = q * 16 + col0;
                const int bbyte = l * 256 + kk * 64 + g4 * 16;
                const bf16x8 bf_ = *(const bf16x8*)(WB + (bbyte ^ ((l & 7) << 4)));
                acc[hh2 * 4 + q] = __builtin_amdgcn_mfma_f32_16x16x32_bf16(af, bf_, acc[hh2 * 4 + q], 0, 0, 0);
            }
        }
    }
#pragma unroll
    for (int f = 0; f < 8; f++) {
        const int col = (f >> 2) * 64 + (f & 3) * 16 + col0;
#pragma unroll
        for (int rg = 0; rg < 4; rg++) {
            const int row = wv * 16 + g4 * 4 + rg;
            out[(size_t)(n0 + row) * HH + col] = f2bf(acc[f][rg]);
        }
    }
}

// ---------------------------------------------------------------------------
// One pass over all edges: dest histogram + masked-edge compaction.
// Hierarchical aggregation: per-wave ballot -> per-block LDS -> ONE global
// atomic per block (256 total) -> coalesced flush. Avoids the R10 regression
// (262K wave-atomics to one address = 111us of idle serialization).
#define CPB 2048   // edges per block; grid = EE / CPB = 256
__global__ __launch_bounds__(256) void k_compact(
    const int* __restrict__ ei, const void* __restrict__ maskp,
    const int* __restrict__ flagp,
    int* __restrict__ count, int* __restrict__ mcount,
    uint2* __restrict__ mrec)
{
    __shared__ uint2 buf[CPB];
    __shared__ int lcnt, gbase;
    const int tid = threadIdx.x;
    const int lane = tid & 63;
    if (tid == 0) lcnt = 0;
    __syncthreads();

    const int base = blockIdx.x * CPB;
    const int mode = *flagp;
#pragma unroll
    for (int i = 0; i < CPB; i += 256) {
        const int e = base + i + tid;
        const int r = ei[e], c = ei[EE + e];
        atomicAdd(&count[c], 1);                       // distributed: fine
        const int msk = get_mask(maskp, mode, e);
        const unsigned long long ball = __ballot(msk);
        const int rank = __popcll(ball & ((1ull << lane) - 1ull));
        int wb = 0;
        if (lane == 0 && ball) wb = atomicAdd(&lcnt, __popcll(ball));
        wb = __shfl(wb, 0, 64);
        if (msk) {
            uint2 rec = {(unsigned)e, (unsigned)r | ((unsigned)c << 16)};
            buf[wb + rank] = rec;
        }
    }
    __syncthreads();
    if (tid == 0) gbase = atomicAdd(mcount, lcnt);     // 256 atomics total
    __syncthreads();
    const int n = lcnt, gb = gbase;
    for (int i = tid; i < n; i += 256)
        mrec[gb + i] = buf[i];
}

// ---------------------------------------------------------------------------
// Edge scores via MFMA over the compacted MASKED edge list only.
__global__ __launch_bounds__(256, 4) void k_edge_score(
    const float* __restrict__ pos, const uint2* __restrict__ mrec,
    const int* __restrict__ mcount,
    const ushort_t* __restrict__ ub, const ushort_t* __restrict__ vb,
    const ushort_t* __restrict__ w1ct, const float* __restrict__ attn_b1,
    const float* __restrict__ attn_w2, const float* __restrict__ attn_b2,
    float* __restrict__ score, unsigned* __restrict__ menc)
{
    __shared__ alignas(16) unsigned char EA[8192];     // bf16[64e][64k], swz ((e&7)<<4)
    __shared__ alignas(16) unsigned char WC[16384];    // bf16[128n][64k], swz ((n&7)<<4)
    __shared__ float dsh[64];
    __shared__ int rsh[64], csh[64], esh[64];
    __shared__ int Em_s;

    const int tid  = threadIdx.x;
    if (tid == 0) Em_s = *mcount;
    __syncthreads();
    const int Em = Em_s;
    const int base = blockIdx.x * 64;
    if (base >= Em) return;

    const int lane = tid & 63;
    const int wv   = tid >> 6;
    const int col0 = lane & 15;
    const int g4   = lane >> 4;

    if (tid < 64) {
        const int slot = base + tid;
        int e = -1, r = 0, c = 0;
        if (slot < Em) {
            const uint2 rec = mrec[slot];
            e = (int)rec.x;
            r = (int)(rec.y & 0xFFFFu);
            c = (int)(rec.y >> 16);
        }
        esh[tid] = e; rsh[tid] = r; csh[tid] = c;
        const float dx = pos[r * 3 + 0] - pos[c * 3 + 0];
        const float dy = pos[r * 3 + 1] - pos[c * 3 + 1];
        const float dz = pos[r * 3 + 2] - pos[c * 3 + 2];
        dsh[tid] = sqrtf(dx * dx + dy * dy + dz * dz);
    }
    for (int p = tid; p < 1024; p += 256) {            // stage WC: 16KB
        const int byte = p * 16;
        const int n = byte >> 7;
        *(float4*)(WC + (byte ^ ((n & 7) << 4))) = *(const float4*)((const char*)w1ct + byte);
    }
    __syncthreads();

    // u/v register prefetch (hidden under EA fill + GEMM)
    int rrv[4], ccv[4];
#pragma unroll
    for (int rg = 0; rg < 4; rg++) {
        const int e = wv * 16 + g4 * 4 + rg;
        rrv[rg] = rsh[e];
        ccv[rg] = csh[e];
    }
    ushort_t ur[4][8], vr[4][8];
#pragma unroll
    for (int rg = 0; rg < 4; rg++)
#pragma unroll
        for (int n = 0; n < 8; n++) {
            ur[rg][n] = ub[(size_t)rrv[rg] * HH + n * 16 + col0];
            vr[rg][n] = vb[(size_t)ccv[rg] * HH + n * 16 + col0];
        }

    // EA fill (bf16 gaussians)
    {
        const int e = tid & 63, jg = tid >> 6;
        const float d = dsh[e];
        for (int jj = jg; jj < 8; jj += 4) {
            bf16x8 pk;
#pragma unroll
            for (int b = 0; b < 8; b++) {
                const int g = jj * 8 + b;
                float val = 0.0f;
                if (g < GG) { const float t = d - g * GSTEP; val = fast_exp2(GC2 * t * t); }
                pk[b] = (short)f2bf(val);
            }
            const int byte = e * 128 + jj * 16;
            *(bf16x8*)(EA + (byte ^ ((e & 7) << 4))) = pk;
        }
    }
    float b1v[8], w2v[8];
#pragma unroll
    for (int n = 0; n < 8; n++) {
        b1v[n] = attn_b1[n * 16 + col0];
        w2v[n] = attn_w2[n * 16 + col0];
    }
    __syncthreads();

    const int m = wv * 16 + col0;
    f32x4 acc[8] = {};
#pragma unroll
    for (int kk = 0; kk < 2; kk++) {
        const int abyte = m * 128 + kk * 64 + g4 * 16;
        const bf16x8 af = *(const bf16x8*)(EA + (abyte ^ ((m & 7) << 4)));
#pragma unroll
        for (int n = 0; n < 8; n++) {
            const int l = n * 16 + col0;
            const int bbyte = l * 128 + kk * 64 + g4 * 16;
            const bf16x8 bf_ = *(const bf16x8*)(WC + (bbyte ^ ((l & 7) << 4)));
            acc[n] = __builtin_amdgcn_mfma_f32_16x16x32_bf16(af, bf_, acc[n], 0, 0, 0);
        }
    }

    float pe[4] = {0.0f, 0.0f, 0.0f, 0.0f};
#pragma unroll
    for (int n = 0; n < 8; n++) {
#pragma unroll
        for (int rg = 0; rg < 4; rg++) {
            float z = acc[n][rg] + bf2f(ur[rg][n]) + bf2f(vr[rg][n]) + b1v[n];
            z = fmaxf(z, 0.0f);
            pe[rg] += z * w2v[n];
        }
    }
#pragma unroll
    for (int mask = 1; mask <= 8; mask <<= 1) {
#pragma unroll
        for (int rg = 0; rg < 4; rg++)
            pe[rg] += __shfl_xor(pe[rg], mask, 64);
    }
    if (col0 == 0) {
        const float b2 = attn_b2[0];
#pragma unroll
        for (int rg = 0; rg < 4; rg++) {
            const int le = wv * 16 + g4 * 4 + rg;
            const int e = esh[le];
            if (e >= 0) {
                const float s = pe[rg] + b2;
                score[e] = s;
                atomicMax(&menc[rsh[le]], fenc(s));
            }
        }
    }
}

// ---------------------------------------------------------------------------
__global__ void k_ssum(const uint2* __restrict__ mrec, const int* __restrict__ mcount,
                       const float* __restrict__ score, const unsigned* __restrict__ menc,
                       float* __restrict__ ssum)
{
    const int slot = blockIdx.x * 256 + threadIdx.x;
    if (slot >= *mcount) return;
    const uint2 rec = mrec[slot];
    const int e = (int)rec.x;
    const int r = (int)(rec.y & 0xFFFFu);
    atomicAdd(&ssum[r], fexpf(score[e] - fdec(menc[r])));
}

// ---------------------------------------------------------------------------
__global__ __launch_bounds__(512) void k_scan(const int* __restrict__ count,
                                              int* __restrict__ cursor)
{
    __shared__ int s[512];
    const int t = threadIdx.x;
    const int base_i = t * 64;
    int sum = 0;
    for (int i = 0; i < 64; i++) sum += count[base_i + i];
    s[t] = sum;
    __syncthreads();
    for (int off = 1; off < 512; off <<= 1) {
        int v = (t >= off) ? s[t - off] : 0;
        __syncthreads();
        s[t] += v;
        __syncthreads();
    }
    int run = s[t] - sum;   // exclusive prefix
    for (int i = 0; i < 64; i++) {
        cursor[base_i + i] = run;
        run += count[base_i + i];
    }
}

// ---------------------------------------------------------------------------
// Scatter edges into dest-sorted order, materializing packed records
// erec[pos] = {d, dec, r|(c<<16), 0}. ssum/menc final before this runs.
__global__ void k_scatter(const int* __restrict__ ei, const void* __restrict__ maskp,
                          const int* __restrict__ flagp, const float* __restrict__ pos,
                          const float* __restrict__ score,
                          const unsigned* __restrict__ menc, const float* __restrict__ ssum,
                          int* __restrict__ cursor, uint4* __restrict__ erec)
{
    const int e = blockIdx.x * 256 + threadIdx.x;
    if (e >= EE) return;
    const int r = ei[e], c = ei[EE + e];
    const int p = atomicAdd(&cursor[c], 1);
    const float dx = pos[r * 3 + 0] - pos[c * 3 + 0];
    const float dy = pos[r * 3 + 1] - pos[c * 3 + 1];
    const float dz = pos[r * 3 + 2] - pos[c * 3 + 2];
    const float d = sqrtf(dx * dx + dy * dy + dz * dz);
    float dec = 1.0f;
    const int mode = *flagp;
    if (get_mask(maskp, mode, e)) {
        const float m = fdec(menc[r]);
        dec = fexpf(score[e] - m) / (ssum[r] + 1e-16f);
    }
    uint4 rec = {__float_as_uint(d), __float_as_uint(dec),
                 (unsigned)r | ((unsigned)c << 16), 0u};
    erec[p] = rec;
}

// ---------------------------------------------------------------------------
// MFMA filter MLP on dest-sorted edge records + LDS segmented reduction.
__global__ __launch_bounds__(256, 4) void k_filter_mfma(
    const uint4* __restrict__ erec,
    const ushort_t* __restrict__ w1t, const float* __restrict__ filt_b1,
    const ushort_t* __restrict__ w2t, const float* __restrict__ filt_b2,
    const ushort_t* __restrict__ xhb, float* __restrict__ agg)
{
    __shared__ alignas(16) unsigned char smem[32768];
    unsigned char* EA = smem;
    unsigned char* W1 = smem + 8192;
    unsigned char* T1 = smem + 16384;
    unsigned char* WB = smem;
    float* msgb = (float*)smem;

    __shared__ float dsh[64], decsh[64], Csh[64];
    __shared__ int rsh[64], csh[64];
    __shared__ int shflags;

    const int tid  = threadIdx.x;
    const int e0   = blockIdx.x * 64;
    const int lane = tid & 63;
    const int wv   = tid >> 6;
    const int col0 = lane & 15;
    const int g4   = lane >> 4;

    // ---- phase A: coalesced record load + stage W1 half0 ----
    if (tid < 64) {
        const uint4 rec = erec[e0 + tid];
        const float d = __uint_as_float(rec.x);
        dsh[tid] = d;
        decsh[tid] = __uint_as_float(rec.y);
        rsh[tid] = (int)(rec.z & 0xFFFFu);
        csh[tid] = (int)(rec.z >> 16);
        Csh[tid] = 0.5f * (cosf(d * PI_OVER_CUT) + 1.0f);
    }
    if (tid == 64) {
        const unsigned cf = erec[e0].z >> 16;
        const unsigned cl = erec[e0 + 63].z >> 16;
        int f = 0;
        if (e0 > 0 && (erec[e0 - 1].z >> 16) == cf) f |= 1;
        if (e0 + 64 < EE && (erec[e0 + 64].z >> 16) == cl) f |= 2;
        shflags = f;
    }
    for (int p = tid; p < 512; p += 256) {       // W1 half0: 8KB
        const int byte = p * 16;
        const int n = byte >> 7;
        *(float4*)(W1 + (byte ^ ((n & 7) << 4))) = *(const float4*)((const char*)w1t + byte);
    }
    __syncthreads();

    // ---- phase B: EA fill + xh register prefetch ----
    {
        const int e = tid & 63, jg = tid >> 6;
        const float d = dsh[e], dec = decsh[e];
        for (int jj = jg; jj < 8; jj += 4) {
            bf16x8 pk;
#pragma unroll
            for (int b = 0; b < 8; b++) {
                const int g = jj * 8 + b;
                float val = 0.0f;
                if (g < GG) { const float t = d - g * GSTEP; val = fast_exp2(GC2 * t * t) * dec; }
                pk[b] = (short)f2bf(val);
            }
            const int byte = e * 128 + jj * 16;
            *(bf16x8*)(EA + (byte ^ ((e & 7) << 4))) = pk;
        }
    }
    int rr[4]; float CC[4];
#pragma unroll
    for (int rg = 0; rg < 4; rg++) {
        const int e = wv * 16 + g4 * 4 + rg;
        rr[rg] = rsh[e];
        CC[rg] = Csh[e];
    }
    ushort_t xr[4][8];                           // issued here, used in epilogue2
#pragma unroll
    for (int rg = 0; rg < 4; rg++)
#pragma unroll
        for (int n = 0; n < 8; n++)
            xr[rg][n] = xhb[(size_t)rr[rg] * HH + n * 16 + col0];
    float b1v[8], b2v[8];
#pragma unroll
    for (int n = 0; n < 8; n++) {
        b1v[n] = filt_b1[n * 16 + col0];
        b2v[n] = filt_b2[n * 16 + col0];
    }
    __syncthreads();

    // ---- GEMM1: T1 = ssp(ea @ w1 + b1), W1 staged in two 8KB halves ----
    const int m = wv * 16 + col0;
    f32x4 acc[8] = {};
#pragma unroll
    for (int h = 0; h < 2; h++) {
        if (h == 1) {
            __syncthreads();
            for (int p = tid; p < 512; p += 256) {
                const int byte = p * 16;
                const int n = byte >> 7;
                *(float4*)(W1 + (byte ^ ((n & 7) << 4))) =
                    *(const float4*)((const char*)w1t + 8192 + byte);
            }
            __syncthreads();
        }
#pragma unroll
        for (int kk = 0; kk < 2; kk++) {
            const int abyte = m * 128 + kk * 64 + g4 * 16;
            const bf16x8 af = *(const bf16x8*)(EA + (abyte ^ ((m & 7) << 4)));
#pragma unroll
            for (int q = 0; q < 4; q++) {
                const int l = q * 16 + col0;
                const int bbyte = l * 128 + kk * 64 + g4 * 16;
                const bf16x8 bf_ = *(const bf16x8*)(W1 + (bbyte ^ ((l & 7) << 4)));
                acc[h * 4 + q] = __builtin_amdgcn_mfma_f32_16x16x32_bf16(af, bf_, acc[h * 4 + q], 0, 0, 0);
            }
        }
    }
    // epilogue1 -> T1 (bf16)
#pragma unroll
    for (int n = 0; n < 8; n++) {
#pragma unroll
        for (int rg = 0; rg < 4; rg++) {
            const int row = wv * 16 + g4 * 4 + rg;
            const float tv = sspf(acc[n][rg] + b1v[n]);
            const int lbyte = row * 256 + (n * 16 + col0) * 2;
            *(ushort_t*)(T1 + (lbyte ^ ((row & 7) << 4))) = f2bf(tv);
        }
    }
    __syncthreads();

    // ---- GEMM2: W = t1 @ w2 + b2, WB staged in two 16KB halves over EA/W1 ----
    f32x4 acc2[8] = {};
#pragma unroll
    for (int h = 0; h < 2; h++) {
        for (int p = tid; p < 1024; p += 256) {
            const int byte = p * 16;
            const int nl = byte >> 8;
            *(float4*)(WB + (byte ^ ((nl & 7) << 4))) =
                *(const float4*)((const char*)w2t + h * 16384 + byte);
        }
        __syncthreads();
#pragma unroll
        for (int kk = 0; kk < 4; kk++) {
            const int abyte = m * 256 + kk * 64 + g4 * 16;
            const bf16x8 af = *(const bf16x8*)(T1 + (abyte ^ ((m & 7) << 4)));
#pragma unroll
            for (int q = 0; q < 4; q++) {
                const int l = q * 16 + col0;
                const int bbyte = l * 256 + kk * 64 + g4 * 16;
                const bf16x8 bf_ = *(const bf16x8*)(WB + (bbyte ^ ((l & 7) << 4)));
                acc2[h * 4 + q] = __builtin_amdgcn_mfma_f32_16x16x32_bf16(af, bf_, acc2[h * 4 + q], 0, 0, 0);
            }
        }
        __syncthreads();
    }

    // ---- epilogue2: msg = xh[r] * (W+b2) * C -> msgb (skewed, overlay) ----
#pragma unroll
    for (int n = 0; n < 8; n++) {
        const int col = n * 16 + col0;
#pragma unroll
        for (int rg = 0; rg < 4; rg++) {
            const int e = wv * 16 + g4 * 4 + rg;
            const float Wv = (acc2[n][rg] + b2v[n]) * CC[rg];
            const float xv = __uint_as_float(((unsigned)xr[rg][n]) << 16);
            msgb[e * 128 + ((col + 8 * g4) & 127)] = xv * Wv;
        }
    }
    __syncthreads();

    // ---- segmented reduction: 2 halves x 32 edges, all 256 threads ----
    {
        const int q = tid >> 7;          // 0 or 1
        const int j = tid & 127;
        const int base = q * 32;
        const int fl = shflags;
        const int cfirst = csh[base], clast = csh[base + 31];
        const int f1 = (q == 0) ? (fl & 1) : (csh[base - 1] == cfirst);
        const int f2 = (q == 1) ? (fl & 2) : (csh[base + 32] == clast);
        float a = msgb[base * 128 + ((j + 8 * ((base >> 2) & 3)) & 127)];
        int cur = cfirst;
        for (int e = base + 1; e < base + 32; e++) {
            const int de = csh[e];
            if (de != cur) {
                if ((cur == cfirst && f1) || (cur == clast && f2))
                    atomicAdd(&agg[(size_t)cur * HH + j], a);
                else
                    agg[(size_t)cur * HH + j] = a;
                a = 0.0f;
                cur = de;
            }
            a += msgb[e * 128 + ((j + 8 * ((e >> 2) & 3)) & 127)];
        }
        if ((cur == cfirst && f1) || (cur == clast && f2))
            atomicAdd(&agg[(size_t)cur * HH + j], a);
        else
            agg[(size_t)cur * HH + j] = a;
    }
}

// ---------------------------------------------------------------------------
// MFMA final: out = ssp(agg @ lin2 + b2) @ lin + b.
__global__ __launch_bounds__(256, 4) void k_final(
    const float* __restrict__ agg, const ushort_t* __restrict__ l2t,
    const float* __restrict__ lin2_b, const ushort_t* __restrict__ lwt,
    const float* __restrict__ lin_b, float* __restrict__ out)
{
    __shared__ alignas(16) unsigned char smem[32768];
    unsigned char* AB = smem;          // bf16[64][128] swz; later T1
    unsigned char* WB = smem + 16384;
    unsigned char* T1 = smem;

    const int tid = threadIdx.x;
    const int n0 = blockIdx.x * 64;

    for (int p = tid; p < 2048; p += 256) {        // stage AB (f32 -> bf16)
        const int row = p >> 5, c4 = p & 31;
        const float4 v = *(const float4*)(agg + (size_t)(n0 + row) * HH + c4 * 4);
        uint2 pk = {(unsigned)f2bf(v.x) | ((unsigned)f2bf(v.y) << 16),
                    (unsigned)f2bf(v.z) | ((unsigned)f2bf(v.w) << 16)};
        const int lbyte = row * 256 + c4 * 8;
        *(uint2*)(AB + (lbyte ^ ((row & 7) << 4))) = pk;
    }
    for (int p = tid; p < 1024; p += 256) {        // stage WB: l2t half0
        const int byte = p * 16; const int nl = byte >> 8;
        *(float4*)(WB + (byte ^ ((nl & 7) << 4))) = *(const float4*)((const char*)l2t + byte);
    }
    __syncthreads();

    const int lane = tid & 63, wv = tid >> 6, col0 = lane & 15, g4 = lane >> 4;
    const int m = wv * 16 + col0;
    float b1v[8], b2v[8];
#pragma unroll
    for (int f = 0; f < 8; f++) {
        const int colf = (f >> 2) * 64 + (f & 3) * 16 + col0;
        b1v[f] = lin2_b[colf];
        b2v[f] = lin_b[colf];
    }

    f32x4 acc[8] = {};
#pragma unroll
    for (int h = 0; h < 2; h++) {
        if (h == 1) {
            __syncthreads();
            for (int p = tid; p < 1024; p += 256) {
                const int byte = p * 16; const int nl = byte >> 8;
                *(float4*)(WB + (byte ^ ((nl & 7) << 4))) =
                    *(const float4*)((const char*)l2t + 16384 + byte);
            }
            __syncthreads();
        }
#pragma unroll
        for (int kk = 0; kk < 4; kk++) {
            const int abyte = m * 256 + kk * 64 + g4 * 16;
            const bf16x8 af = *(const bf16x8*)(AB + (abyte ^ ((m & 7) << 4)));
#pragma unroll
            for (int q = 0; q < 4; q++) {
                const int l = q * 16 + col0;
                const int bbyte = l * 256 + kk * 64 + g4 * 16;
                const bf16x8 bf_ = *(const bf16x8*)(WB + (bbyte ^ ((l & 7) << 4)));
                acc[h * 4 + q] = __builtin_amdgcn_mfma_f32_16x16x32_bf16(af, bf_, acc[h * 4 + q], 0, 0, 0);
            }
        }
    }
    __syncthreads();   // all GEMM1 reads done; AB may be overlaid by T1

    // T2 = ssp(acc + b1) -> T1 (bf16); stage WB: lwt half0 in parallel
#pragma unroll
    for (int f = 0; f < 8; f++) {
        const int colf = (f >> 2) * 64 + (f & 3) * 16 + col0;
#pragma unroll
        for (int rg = 0; rg < 4; rg++) {
            const int row = wv * 16 + g4 * 4 + rg;
            const float tv = sspf(acc[f][rg] + b1v[f]);
            const int lbyte = row * 256 + colf * 2;
            *(ushort_t*)(T1 + (lbyte ^ ((row & 7) << 4))) = f2bf(tv);
        }
    }
    for (int p = tid; p < 1024; p += 256) {
        const int byte = p * 16; const int nl = byte >> 8;
        *(float4*)(WB + (byte ^ ((nl & 7) << 4))) = *(const float4*)((const char*)lwt + byte);
    }
    __syncthreads();

    f32x4 acc2[8] = {};
#pragma unroll
    for (int h = 0; h < 2; h++) {
        if (h == 1) {
            __syncthreads();
            for (int p = tid; p < 1024; p += 256) {
                const int byte = p * 16; const int nl = byte >> 8;
                *(float4*)(WB + (byte ^ ((nl & 7) << 4))) =
                    *(const float4*)((const char*)lwt + 16384 + byte);
            }
            __syncthreads();
        }
#pragma unroll
        for (int kk = 0; kk < 4; kk++) {
            const int abyte = m * 256 + kk * 64 + g4 * 16;
            const bf16x8 af = *(const bf16x8*)(T1 + (abyte ^ ((m & 7) << 4)));
#pragma unroll
            for (int q = 0; q < 4; q++) {
                const int l = q * 16 + col0;
                const int bbyte = l * 256 + kk * 64 + g4 * 16;
                const bf16x8 bf_ = *(const bf16x8*)(WB + (bbyte ^ ((l & 7) << 4)));
                acc2[h * 4 + q] = __builtin_amdgcn_mfma_f32_16x16x32_bf16(af, bf_, acc2[h * 4 + q], 0, 0, 0);
            }
        }
    }
#pragma unroll
    for (int f = 0; f < 8; f++) {
        const int colf = (f >> 2) * 64 + (f & 3) * 16 + col0;
#pragma unroll
        for (int rg = 0; rg < 4; rg++) {
            const int row = wv * 16 + g4 * 4 + rg;
            out[(size_t)(n0 + row) * HH + colf] = acc2[f][rg] + b2v[f];
        }
    }
}

// ---------------------------------------------------------------------------
__global__ void k_copy_pos(const float* __restrict__ pos, float* __restrict__ out) {
    const int i = blockIdx.x * 256 + threadIdx.x;
    if (i < NN * 3) out[i] = pos[i];
}

// ---------------------------------------------------------------------------
extern "C" void kernel_launch(void* const* d_in, const int* in_sizes, int n_in,
                              void* d_out, int out_size, void* d_ws, size_t ws_size,
                              hipStream_t stream)
{
    const float* h       = (const float*)d_in[0];
    const float* pos     = (const float*)d_in[1];
    const int*   ei      = (const int*)d_in[2];
    const void*  maskp   = d_in[3];
    const float* attn_w1 = (const float*)d_in[4];
    const float* attn_b1 = (const float*)d_in[5];
    const float* attn_w2 = (const float*)d_in[6];
    const float* attn_b2 = (const float*)d_in[7];
    const float* filt_w1 = (const float*)d_in[8];
    const float* filt_b1 = (const float*)d_in[9];
    const float* filt_w2 = (const float*)d_in[10];
    const float* filt_b2 = (const float*)d_in[11];
    const float* lin1_w  = (const float*)d_in[12];
    const float* lin2_w  = (const float*)d_in[13];
    const float* lin2_b  = (const float*)d_in[14];
    const float* lin_w   = (const float*)d_in[15];
    const float* lin_b   = (const float*)d_in[16];

    char* p = (char*)d_ws;
    auto alloc = [&](size_t bytes) { char* r = p; p += (bytes + 255) & ~(size_t)255; return r; };

    ushort_t* ub    = (ushort_t*)alloc((size_t)NN * HH * 2);
    ushort_t* vb    = (ushort_t*)alloc((size_t)NN * HH * 2);
    ushort_t* xhb   = (ushort_t*)alloc((size_t)NN * HH * 2);
    float*    score = (float*)alloc((size_t)EE * 4);
    unsigned* menc  = (unsigned*)alloc((size_t)NN * 4);   // menc/ssum/count/mcount
    float*    ssum  = (float*)alloc((size_t)NN * 4);      // contiguous zero block
    int*      count = (int*)alloc((size_t)NN * 4);
    int*      mcount= (int*)alloc(4);
    int*      cursor= (int*)alloc((size_t)NN * 4);
    float*    agg   = (float*)alloc((size_t)NN * HH * 4);
    int*      flag  = (int*)alloc(4);
    uint2*    mrec  = (uint2*)alloc((size_t)EE * 8);
    uint4*    erec  = (uint4*)alloc((size_t)EE * 16);
    ushort_t* w1t   = (ushort_t*)alloc((size_t)128 * 64 * 2);
    ushort_t* w1ct  = (ushort_t*)alloc((size_t)128 * 64 * 2);
    ushort_t* w2t   = (ushort_t*)alloc((size_t)128 * 128 * 2);
    ushort_t* wut   = (ushort_t*)alloc((size_t)128 * 128 * 2);
    ushort_t* wvt   = (ushort_t*)alloc((size_t)128 * 128 * 2);
    ushort_t* wxt   = (ushort_t*)alloc((size_t)128 * 128 * 2);
    ushort_t* l2t   = (ushort_t*)alloc((size_t)128 * 128 * 2);
    ushort_t* lwt   = (ushort_t*)alloc((size_t)128 * 128 * 2);

    float* out_h   = (float*)d_out;
    float* out_pos = out_h + (size_t)NN * HH;

    hipMemsetAsync(menc, 0, (size_t)3 * NN * 4 + 256, stream);  // menc+ssum+count+mcount

    k_detect<<<1, 256, 0, stream>>>((const unsigned char*)maskp, flag);
    k_prep_w<<<448, 256, 0, stream>>>(filt_w1, filt_w2, attn_w1, lin1_w, lin2_w, lin_w,
                                      w1t, w1ct, w2t, wut, wvt, wxt, l2t, lwt);
    k_node_proj<<<dim3(NN / 64, 3), 256, 0, stream>>>(h, wut, wvt, wxt, ub, vb, xhb);
    k_compact<<<EE / CPB, 256, 0, stream>>>(ei, maskp, flag, count, mcount, mrec);
    k_edge_score<<<EE / 64, 256, 0, stream>>>(pos, mrec, mcount, ub, vb,
                                              w1ct, attn_b1, attn_w2, attn_b2,
                                              score, menc);
    k_ssum<<<EE / 256, 256, 0, stream>>>(mrec, mcount, score, menc, ssum);
    k_scan<<<1, 512, 0, stream>>>(count, cursor);
    k_scatter<<<EE / 256, 256, 0, stream>>>(ei, maskp, flag, pos, score, menc, ssum,
                                            cursor, erec);

    hipMemsetAsync(agg, 0, (size_t)NN * HH * sizeof(float), stream);
    k_filter_mfma<<<EE / 64, 256, 0, stream>>>(erec, w1t, filt_b1, w2t, filt_b2, xhb, agg);

    k_final<<<NN / 64, 256, 0, stream>>>(agg, l2t, lin2_b, lwt, lin_b, out_h);
    k_copy_pos<<<(NN * 3 + 255) / 256, 256, 0, stream>>>(pos, out_pos);
}

// Round 12
// 290.212 us; speedup vs baseline: 1.3878x; 1.0817x over previous
//
#include <hip/hip_runtime.h>

#define NN 32768
#define HH 128
#define GG 50
#define EE 524288
#define TBINS 8192

constexpr float GSTEP = 10.0f / 49.0f;
constexpr float GCOEF = -0.5f / (GSTEP * GSTEP);
constexpr float PI_OVER_CUT = 0.31415926535897931f;   // pi / 10
constexpr float LOG2F_ = 0.69314718055994531f;
constexpr float LOG2E_ = 1.4426950408889634f;
constexpr float RLOG2E_ = 0.69314718055994531f;
constexpr float GC2 = GCOEF * LOG2E_;                 // gaussian exp -> exp2
constexpr float DMAX_ = 17.4f;                        // > sqrt(300)
constexpr float BIN_SCALE = (float)TBINS / DMAX_;
constexpr float BIN_INV   = DMAX_ / (float)TBINS;

typedef __attribute__((ext_vector_type(8))) short bf16x8;
typedef __attribute__((ext_vector_type(4))) float f32x4;
typedef unsigned short ushort_t;

__device__ __forceinline__ float fast_exp2(float x) {
    float r; asm("v_exp_f32 %0, %1" : "=v"(r) : "v"(x)); return r;
}
__device__ __forceinline__ float fast_log2(float x) {
    float r; asm("v_log_f32 %0, %1" : "=v"(r) : "v"(x)); return r;
}
__device__ __forceinline__ float fexpf(float x) {      // e^x via v_exp_f32
    return fast_exp2(x * LOG2E_);
}
__device__ __forceinline__ float sspf(float x) {       // softplus(x) - log2
    const float p = fast_exp2(x * LOG2E_);
    const float r = RLOG2E_ * fast_log2(1.0f + p) - LOG2F_;
    return (x > 80.0f) ? (x - LOG2F_) : r;
}
__device__ __forceinline__ unsigned fenc(float f) {
    unsigned b = __float_as_uint(f);
    return (b & 0x80000000u) ? ~b : (b | 0x80000000u);
}
__device__ __forceinline__ float fdec(unsigned u) {
    unsigned b = (u & 0x80000000u) ? (u ^ 0x80000000u) : ~u;
    return __uint_as_float(b);
}
__device__ __forceinline__ int get_mask(const void* mp, int mode, int e) {
    if (mode) return ((const unsigned char*)mp)[e] != 0;
    return ((const int*)mp)[e] != 0;
}
__device__ __forceinline__ ushort_t f2bf(float f) {   // RNE f32 -> bf16
    unsigned u = __float_as_uint(f);
    return (ushort_t)((u + 0x7FFFu + ((u >> 16) & 1u)) >> 16);
}
__device__ __forceinline__ float bf2f(ushort_t s) { return __uint_as_float(((unsigned)s) << 16); }

// ---------------------------------------------------------------------------
__global__ void k_detect(const unsigned char* __restrict__ mb, int* __restrict__ flag) {
    __shared__ int any;
    if (threadIdx.x == 0) any = 0;
    __syncthreads();
    int local = 0;
    for (int i = threadIdx.x; i < 16384; i += blockDim.x)
        if ((i & 3) != 0 && mb[i]) local = 1;
    if (local) atomicOr(&any, 1);
    __syncthreads();
    if (threadIdx.x == 0) *flag = any;   // 1 => byte mode, 0 => int32 mode
}

// ---------------------------------------------------------------------------
// One-time: transpose weights to bf16 [n][k] layouts.
__global__ void k_prep_w(const float* __restrict__ filt_w2,
                         const float* __restrict__ attn_w1, const float* __restrict__ lin1_w,
                         const float* __restrict__ lin2_w, const float* __restrict__ lin_w,
                         ushort_t* __restrict__ w2t, ushort_t* __restrict__ wut,
                         ushort_t* __restrict__ wvt, ushort_t* __restrict__ wxt,
                         ushort_t* __restrict__ l2t, ushort_t* __restrict__ lwt)
{
    const int t = blockIdx.x * 256 + threadIdx.x;
    if (t < 16384) {                         // w2t[n][k]
        const int n = t >> 7, k = t & 127;
        w2t[t] = f2bf(filt_w2[k * HH + n]);
    } else if (t < 32768) {                  // wut[n][k] = attn_w1 rows 0..127
        const int i = t - 16384, n = i >> 7, k = i & 127;
        wut[i] = f2bf(attn_w1[(size_t)k * HH + n]);
    } else if (t < 49152) {                  // wvt[n][k] = attn_w1 rows 128..255
        const int i = t - 32768, n = i >> 7, k = i & 127;
        wvt[i] = f2bf(attn_w1[(size_t)(128 + k) * HH + n]);
    } else if (t < 65536) {                  // wxt[n][k] = lin1_w
        const int i = t - 49152, n = i >> 7, k = i & 127;
        wxt[i] = f2bf(lin1_w[(size_t)k * HH + n]);
    } else if (t < 81920) {                  // l2t[n][k] = lin2_w
        const int i = t - 65536, n = i >> 7, k = i & 127;
        l2t[i] = f2bf(lin2_w[(size_t)k * HH + n]);
    } else if (t < 98304) {                  // lwt[n][k] = lin_w
        const int i = t - 81920, n = i >> 7, k = i & 127;
        lwt[i] = f2bf(lin_w[(size_t)k * HH + n]);
    }
}

// ---------------------------------------------------------------------------
// Tabulate the 1-D d-functions: atab[bin][j] = gauss(d_bin)@filt_w1 (no bias),
// btab[bin][j] = gauss(d_bin)@attn_w1C + attn_b1. 2 bins per block.
__global__ __launch_bounds__(256) void k_prep_tab(
    const float* __restrict__ filt_w1, const float* __restrict__ attn_w1,
    const float* __restrict__ attn_b1,
    ushort_t* __restrict__ atab, ushort_t* __restrict__ btab)
{
    __shared__ float ga[2][GG];
    const int tid = threadIdx.x;
    const int half = tid >> 7, j = tid & 127;
    const int bin = blockIdx.x * 2 + half;
    const float d = bin * BIN_INV;
    if (j < GG) {
        const float t = d - j * GSTEP;
        ga[half][j] = fast_exp2(GC2 * t * t);
    }
    __syncthreads();
    float a = 0.0f, b = attn_b1[j];
    for (int g = 0; g < GG; g++) {
        const float gv = ga[half][g];
        a += gv * filt_w1[g * HH + j];
        b += gv * attn_w1[(size_t)(256 + g) * HH + j];
    }
    atab[(size_t)bin * HH + j] = f2bf(a);
    btab[(size_t)bin * HH + j] = f2bf(b);
}

// ---------------------------------------------------------------------------
// MFMA node projections: out = bf16(h @ W) for W in {attn_u, attn_v, lin1}.
__global__ __launch_bounds__(256, 4) void k_node_proj(
    const float* __restrict__ h,
    const ushort_t* __restrict__ wut, const ushort_t* __restrict__ wvt,
    const ushort_t* __restrict__ wxt,
    ushort_t* __restrict__ ub, ushort_t* __restrict__ vb, ushort_t* __restrict__ xhb)
{
    __shared__ alignas(16) unsigned char smem[32768];
    unsigned char* HB = smem;          // bf16[64][128], swz ((row&7)<<4)
    unsigned char* WB = smem + 16384;  // bf16[64n][128k] half, swz ((n&7)<<4)

    const int tid = threadIdx.x;
    const int n0 = blockIdx.x * 64;
    const int mat = blockIdx.y;
    const ushort_t* __restrict__ wt = (mat == 0) ? wut : (mat == 1 ? wvt : wxt);
    ushort_t* __restrict__ out = (mat == 0) ? ub : (mat == 1 ? vb : xhb);

    for (int p = tid; p < 2048; p += 256) {        // stage HB (f32 -> bf16)
        const int row = p >> 5, c4 = p & 31;
        const float4 v = *(const float4*)(h + (size_t)(n0 + row) * HH + c4 * 4);
        uint2 pk = {(unsigned)f2bf(v.x) | ((unsigned)f2bf(v.y) << 16),
                    (unsigned)f2bf(v.z) | ((unsigned)f2bf(v.w) << 16)};
        const int lbyte = row * 256 + c4 * 8;
        *(uint2*)(HB + (lbyte ^ ((row & 7) << 4))) = pk;
    }
    for (int p = tid; p < 1024; p += 256) {        // stage WB half0
        const int byte = p * 16; const int nl = byte >> 8;
        *(float4*)(WB + (byte ^ ((nl & 7) << 4))) = *(const float4*)((const char*)wt + byte);
    }
    __syncthreads();

    const int lane = tid & 63, wv = tid >> 6, col0 = lane & 15, g4 = lane >> 4;
    const int m = wv * 16 + col0;
    f32x4 acc[8] = {};
#pragma unroll
    for (int hh2 = 0; hh2 < 2; hh2++) {
        if (hh2 == 1) {
            __syncthreads();
            for (int p = tid; p < 1024; p += 256) {
                const int byte = p * 16; const int nl = byte >> 8;
                *(float4*)(WB + (byte ^ ((nl & 7) << 4))) =
                    *(const float4*)((const char*)wt + 16384 + byte);
            }
            __syncthreads();
        }
#pragma unroll
        for (int kk = 0; kk < 4; kk++) {
            const int abyte = m * 256 + kk * 64 + g4 * 16;
            const bf16x8 af = *(const bf16x8*)(HB + (abyte ^ ((m & 7) << 4)));
#pragma unroll
            for (int q = 0; q < 4; q++) {
                const int l = q * 16 + col0;
                const int bbyte = l * 256 + kk * 64 + g4 * 16;
                const bf16x8 bf_ = *(const bf16x8*)(WB + (bbyte ^ ((l & 7) << 4)));
                acc[hh2 * 4 + q] = __builtin_amdgcn_mfma_f32_16x16x32_bf16(af, bf_, acc[hh2 * 4 + q], 0, 0, 0);
            }
        }
    }
#pragma unroll
    for (int f = 0; f < 8; f++) {
        const int col = (f >> 2) * 64 + (f & 3) * 16 + col0;
#pragma unroll
        for (int rg = 0; rg < 4; rg++) {
            const int row = wv * 16 + g4 * 4 + rg;
            out[(size_t)(n0 + row) * HH + col] = f2bf(acc[f][rg]);
        }
    }
}

// ---------------------------------------------------------------------------
// One pass over all edges: dest histogram + masked-edge compaction.
#define CPB 2048   // edges per block; grid = EE / CPB = 256
__global__ __launch_bounds__(256) void k_compact(
    const int* __restrict__ ei, const void* __restrict__ maskp,
    const int* __restrict__ flagp,
    int* __restrict__ count, int* __restrict__ mcount,
    uint2* __restrict__ mrec)
{
    __shared__ uint2 buf[CPB];
    __shared__ int lcnt, gbase;
    const int tid = threadIdx.x;
    const int lane = tid & 63;
    if (tid == 0) lcnt = 0;
    __syncthreads();

    const int base = blockIdx.x * CPB;
    const int mode = *flagp;
#pragma unroll
    for (int i = 0; i < CPB; i += 256) {
        const int e = base + i + tid;
        const int r = ei[e], c = ei[EE + e];
        atomicAdd(&count[c], 1);                       // distributed: fine
        const int msk = get_mask(maskp, mode, e);
        const unsigned long long ball = __ballot(msk);
        const int rank = __popcll(ball & ((1ull << lane) - 1ull));
        int wb = 0;
        if (lane == 0 && ball) wb = atomicAdd(&lcnt, __popcll(ball));
        wb = __shfl(wb, 0, 64);
        if (msk) {
            uint2 rec = {(unsigned)e, (unsigned)r | ((unsigned)c << 16)};
            buf[wb + rank] = rec;
        }
    }
    __syncthreads();
    if (tid == 0) gbase = atomicAdd(mcount, lcnt);     // 256 atomics total
    __syncthreads();
    const int n = lcnt, gb = gbase;
    for (int i = tid; i < n; i += 256)
        mrec[gb + i] = buf[i];
}

// ---------------------------------------------------------------------------
// Edge scores over the compacted MASKED list, table-based (no GEMM):
// score = w2 . relu(u[r] + v[c] + B(d)) + b2   (b1 folded into Btab).
// Lane layout: each lane handles 8 CONTIGUOUS cols [col0*8, col0*8+8).
__global__ __launch_bounds__(256, 8) void k_edge_score(
    const float* __restrict__ pos, const uint2* __restrict__ mrec,
    const int* __restrict__ mcount,
    const ushort_t* __restrict__ ub, const ushort_t* __restrict__ vb,
    const ushort_t* __restrict__ btab,
    const float* __restrict__ attn_w2, const float* __restrict__ attn_b2,
    float* __restrict__ score, unsigned* __restrict__ menc)
{
    __shared__ int rsh[64], csh[64], esh[64], bsh[64];
    __shared__ int Em_s;

    const int tid  = threadIdx.x;
    if (tid == 0) Em_s = *mcount;
    __syncthreads();
    const int Em = Em_s;
    const int base = blockIdx.x * 64;
    if (base >= Em) return;

    const int lane = tid & 63;
    const int wv   = tid >> 6;
    const int col0 = lane & 15;
    const int g4   = lane >> 4;

    if (tid < 64) {
        const int slot = base + tid;
        int e = -1, r = 0, c = 0;
        if (slot < Em) {
            const uint2 rec = mrec[slot];
            e = (int)rec.x;
            r = (int)(rec.y & 0xFFFFu);
            c = (int)(rec.y >> 16);
        }
        esh[tid] = e; rsh[tid] = r; csh[tid] = c;
        const float dx = pos[r * 3 + 0] - pos[c * 3 + 0];
        const float dy = pos[r * 3 + 1] - pos[c * 3 + 1];
        const float dz = pos[r * 3 + 2] - pos[c * 3 + 2];
        const float d = sqrtf(dx * dx + dy * dy + dz * dz);
        int bin = (int)(d * BIN_SCALE + 0.5f);
        bsh[tid] = (bin > TBINS - 1) ? TBINS - 1 : bin;
    }
    __syncthreads();

    const float4 w20 = *(const float4*)(attn_w2 + col0 * 8);
    const float4 w21 = *(const float4*)(attn_w2 + col0 * 8 + 4);
    const float w2v[8] = {w20.x, w20.y, w20.z, w20.w, w21.x, w21.y, w21.z, w21.w};

    float pe[4];
#pragma unroll
    for (int rg = 0; rg < 4; rg++) {
        const int le = wv * 16 + g4 * 4 + rg;
        const int r = rsh[le], c = csh[le], bin = bsh[le];
        const bf16x8 uu = *(const bf16x8*)(ub + (size_t)r * HH + col0 * 8);
        const bf16x8 vv = *(const bf16x8*)(vb + (size_t)c * HH + col0 * 8);
        const bf16x8 bb = *(const bf16x8*)(btab + (size_t)bin * HH + col0 * 8);
        float s = 0.0f;
#pragma unroll
        for (int b = 0; b < 8; b++) {
            float z = bf2f((ushort_t)uu[b]) + bf2f((ushort_t)vv[b]) + bf2f((ushort_t)bb[b]);
            z = fmaxf(z, 0.0f);
            s += z * w2v[b];
        }
        pe[rg] = s;
    }
#pragma unroll
    for (int mask = 1; mask <= 8; mask <<= 1) {
#pragma unroll
        for (int rg = 0; rg < 4; rg++)
            pe[rg] += __shfl_xor(pe[rg], mask, 64);
    }
    if (col0 == 0) {
        const float b2 = attn_b2[0];
#pragma unroll
        for (int rg = 0; rg < 4; rg++) {
            const int le = wv * 16 + g4 * 4 + rg;
            const int e = esh[le];
            if (e >= 0) {
                const float s = pe[rg] + b2;
                score[e] = s;
                atomicMax(&menc[rsh[le]], fenc(s));
            }
        }
    }
}

// ---------------------------------------------------------------------------
__global__ void k_ssum(const uint2* __restrict__ mrec, const int* __restrict__ mcount,
                       const float* __restrict__ score, const unsigned* __restrict__ menc,
                       float* __restrict__ ssum)
{
    const int slot = blockIdx.x * 256 + threadIdx.x;
    if (slot >= *mcount) return;
    const uint2 rec = mrec[slot];
    const int e = (int)rec.x;
    const int r = (int)(rec.y & 0xFFFFu);
    atomicAdd(&ssum[r], fexpf(score[e] - fdec(menc[r])));
}

// ---------------------------------------------------------------------------
__global__ __launch_bounds__(512) void k_scan(const int* __restrict__ count,
                                              int* __restrict__ cursor)
{
    __shared__ int s[512];
    const int t = threadIdx.x;
    const int base_i = t * 64;
    int sum = 0;
    for (int i = 0; i < 64; i++) sum += count[base_i + i];
    s[t] = sum;
    __syncthreads();
    for (int off = 1; off < 512; off <<= 1) {
        int v = (t >= off) ? s[t - off] : 0;
        __syncthreads();
        s[t] += v;
        __syncthreads();
    }
    int run = s[t] - sum;   // exclusive prefix
    for (int i = 0; i < 64; i++) {
        cursor[base_i + i] = run;
        run += count[base_i + i];
    }
}

// ---------------------------------------------------------------------------
// Scatter edges into dest-sorted order: erec[pos] = {d, dec, r|(c<<16), bin}.
__global__ void k_scatter(const int* __restrict__ ei, const void* __restrict__ maskp,
                          const int* __restrict__ flagp, const float* __restrict__ pos,
                          const float* __restrict__ score,
                          const unsigned* __restrict__ menc, const float* __restrict__ ssum,
                          int* __restrict__ cursor, uint4* __restrict__ erec)
{
    const int e = blockIdx.x * 256 + threadIdx.x;
    if (e >= EE) return;
    const int r = ei[e], c = ei[EE + e];
    const int p = atomicAdd(&cursor[c], 1);
    const float dx = pos[r * 3 + 0] - pos[c * 3 + 0];
    const float dy = pos[r * 3 + 1] - pos[c * 3 + 1];
    const float dz = pos[r * 3 + 2] - pos[c * 3 + 2];
    const float d = sqrtf(dx * dx + dy * dy + dz * dz);
    int bin = (int)(d * BIN_SCALE + 0.5f);
    bin = (bin > TBINS - 1) ? TBINS - 1 : bin;
    float dec = 1.0f;
    const int mode = *flagp;
    if (get_mask(maskp, mode, e)) {
        const float m = fdec(menc[r]);
        dec = fexpf(score[e] - m) / (ssum[r] + 1e-16f);
    }
    uint4 rec = {__float_as_uint(d), __float_as_uint(dec),
                 (unsigned)r | ((unsigned)c << 16), (unsigned)bin};
    erec[p] = rec;
}

// ---------------------------------------------------------------------------
// Filter on dest-sorted records: T1 = ssp(dec*A(d)+b1) from table (no GEMM1),
// GEMM2 on MFMA, LDS segmented reduction.
__global__ __launch_bounds__(256, 4) void k_filter_mfma(
    const uint4* __restrict__ erec,
    const ushort_t* __restrict__ atab, const float* __restrict__ filt_b1,
    const ushort_t* __restrict__ w2t, const float* __restrict__ filt_b2,
    const ushort_t* __restrict__ xhb, float* __restrict__ agg)
{
    __shared__ alignas(16) unsigned char smem[32768];
    unsigned char* T1 = smem;            // bf16[64e][128k], swz ((e&7)<<4)
    unsigned char* WB = smem + 16384;    // bf16[64n][128k] half, swz ((n&7)<<4)
    float* msgb = (float*)smem;          // f32[64][128] overlay after GEMM2

    __shared__ float decsh[64], Csh[64];
    __shared__ int rsh[64], csh[64], bsh[64];
    __shared__ int shflags;

    const int tid  = threadIdx.x;
    const int e0   = blockIdx.x * 64;
    const int lane = tid & 63;
    const int wv   = tid >> 6;
    const int col0 = lane & 15;
    const int g4   = lane >> 4;

    // ---- phase A: record load + WB half0 staging ----
    if (tid < 64) {
        const uint4 rec = erec[e0 + tid];
        const float d = __uint_as_float(rec.x);
        decsh[tid] = __uint_as_float(rec.y);
        rsh[tid] = (int)(rec.z & 0xFFFFu);
        csh[tid] = (int)(rec.z >> 16);
        bsh[tid] = (int)rec.w;
        Csh[tid] = 0.5f * (cosf(d * PI_OVER_CUT) + 1.0f);
    }
    if (tid == 64) {
        const unsigned cf = erec[e0].z >> 16;
        const unsigned cl = erec[e0 + 63].z >> 16;
        int f = 0;
        if (e0 > 0 && (erec[e0 - 1].z >> 16) == cf) f |= 1;
        if (e0 + 64 < EE && (erec[e0 + 64].z >> 16) == cl) f |= 2;
        shflags = f;
    }
    for (int p = tid; p < 1024; p += 256) {      // WB half0: 16KB
        const int byte = p * 16; const int nl = byte >> 8;
        *(float4*)(WB + (byte ^ ((nl & 7) << 4))) = *(const float4*)((const char*)w2t + byte);
    }
    __syncthreads();

    // ---- phase B: T1 fill from atab + xh register prefetch ----
    {
        const int e = tid & 63, q = tid >> 6;
        const float dec = decsh[e];
        const ushort_t* arow = atab + (size_t)bsh[e] * HH;
#pragma unroll
        for (int c8 = 0; c8 < 4; c8++) {
            const int col = q * 32 + c8 * 8;
            const bf16x8 av = *(const bf16x8*)(arow + col);
            const float4 fb0 = *(const float4*)(filt_b1 + col);
            const float4 fb1 = *(const float4*)(filt_b1 + col + 4);
            const float bb[8] = {fb0.x, fb0.y, fb0.z, fb0.w, fb1.x, fb1.y, fb1.z, fb1.w};
            bf16x8 pk;
#pragma unroll
            for (int b = 0; b < 8; b++)
                pk[b] = (short)f2bf(sspf(dec * bf2f((ushort_t)av[b]) + bb[b]));
            const int lbyte = e * 256 + col * 2;
            *(bf16x8*)(T1 + (lbyte ^ ((e & 7) << 4))) = pk;
        }
    }
    int rr[4]; float CC[4];
#pragma unroll
    for (int rg = 0; rg < 4; rg++) {
        const int e = wv * 16 + g4 * 4 + rg;
        rr[rg] = rsh[e];
        CC[rg] = Csh[e];
    }
    ushort_t xr[4][8];                           // MFMA-col-layout gather
#pragma unroll
    for (int rg = 0; rg < 4; rg++)
#pragma unroll
        for (int n = 0; n < 8; n++)
            xr[rg][n] = xhb[(size_t)rr[rg] * HH + n * 16 + col0];
    float b2v[8];
#pragma unroll
    for (int n = 0; n < 8; n++)
        b2v[n] = filt_b2[n * 16 + col0];
    __syncthreads();

    // ---- GEMM2: W = t1 @ w2, WB in two 16KB halves ----
    const int m = wv * 16 + col0;
    f32x4 acc2[8] = {};
#pragma unroll
    for (int kk = 0; kk < 4; kk++) {
        const int abyte = m * 256 + kk * 64 + g4 * 16;
        const bf16x8 af = *(const bf16x8*)(T1 + (abyte ^ ((m & 7) << 4)));
#pragma unroll
        for (int q = 0; q < 4; q++) {
            const int l = q * 16 + col0;
            const int bbyte = l * 256 + kk * 64 + g4 * 16;
            const bf16x8 bf_ = *(const bf16x8*)(WB + (bbyte ^ ((l & 7) << 4)));
            acc2[q] = __builtin_amdgcn_mfma_f32_16x16x32_bf16(af, bf_, acc2[q], 0, 0, 0);
        }
    }
    __syncthreads();
    for (int p = tid; p < 1024; p += 256) {      // WB half1
        const int byte = p * 16; const int nl = byte >> 8;
        *(float4*)(WB + (byte ^ ((nl & 7) << 4))) =
            *(const float4*)((const char*)w2t + 16384 + byte);
    }
    __syncthreads();
#pragma unroll
    for (int kk = 0; kk < 4; kk++) {
        const int abyte = m * 256 + kk * 64 + g4 * 16;
        const bf16x8 af = *(const bf16x8*)(T1 + (abyte ^ ((m & 7) << 4)));
#pragma unroll
        for (int q = 0; q < 4; q++) {
            const int l = q * 16 + col0;
            const int bbyte = l * 256 + kk * 64 + g4 * 16;
            const bf16x8 bf_ = *(const bf16x8*)(WB + (bbyte ^ ((l & 7) << 4)));
            acc2[4 + q] = __builtin_amdgcn_mfma_f32_16x16x32_bf16(af, bf_, acc2[4 + q], 0, 0, 0);
        }
    }
    __syncthreads();   // T1/WB dead; msgb overlay

    // ---- epilogue2: msg = xh[r] * (W+b2) * C -> msgb (skewed) ----
#pragma unroll
    for (int n = 0; n < 8; n++) {
        const int col = n * 16 + col0;
#pragma unroll
        for (int rg = 0; rg < 4; rg++) {
            const int e = wv * 16 + g4 * 4 + rg;
            const float Wv = (acc2[n][rg] + b2v[n]) * CC[rg];
            const float xv = __uint_as_float(((unsigned)xr[rg][n]) << 16);
            msgb[e * 128 + ((col + 8 * g4) & 127)] = xv * Wv;
        }
    }
    __syncthreads();

    // ---- segmented reduction: 2 halves x 32 edges, all 256 threads ----
    {
        const int q = tid >> 7;          // 0 or 1
        const int j = tid & 127;
        const int base = q * 32;
        const int fl = shflags;
        const int cfirst = csh[base], clast = csh[base + 31];
        const int f1 = (q == 0) ? (fl & 1) : (csh[base - 1] == cfirst);
        const int f2 = (q == 1) ? (fl & 2) : (csh[base + 32] == clast);
        float a = msgb[base * 128 + ((j + 8 * ((base >> 2) & 3)) & 127)];
        int cur = cfirst;
        for (int e = base + 1; e < base + 32; e++) {
            const int de = csh[e];
            if (de != cur) {
                if ((cur == cfirst && f1) || (cur == clast && f2))
                    atomicAdd(&agg[(size_t)cur * HH + j], a);
                else
                    agg[(size_t)cur * HH + j] = a;
                a = 0.0f;
                cur = de;
            }
            a += msgb[e * 128 + ((j + 8 * ((e >> 2) & 3)) & 127)];
        }
        if ((cur == cfirst && f1) || (cur == clast && f2))
            atomicAdd(&agg[(size_t)cur * HH + j], a);
        else
            agg[(size_t)cur * HH + j] = a;
    }
}

// ---------------------------------------------------------------------------
// MFMA final: out = ssp(agg @ lin2 + b2) @ lin + b.
__global__ __launch_bounds__(256, 4) void k_final(
    const float* __restrict__ agg, const ushort_t* __restrict__ l2t,
    const float* __restrict__ lin2_b, const ushort_t* __restrict__ lwt,
    const float* __restrict__ lin_b, float* __restrict__ out)
{
    __shared__ alignas(16) unsigned char smem[32768];
    unsigned char* AB = smem;          // bf16[64][128] swz; later T1
    unsigned char* WB = smem + 16384;
    unsigned char* T1 = smem;

    const int tid = threadIdx.x;
    const int n0 = blockIdx.x * 64;

    for (int p = tid; p < 2048; p += 256) {        // stage AB (f32 -> bf16)
        const int row = p >> 5, c4 = p & 31;
        const float4 v = *(const float4*)(agg + (size_t)(n0 + row) * HH + c4 * 4);
        uint2 pk = {(unsigned)f2bf(v.x) | ((unsigned)f2bf(v.y) << 16),
                    (unsigned)f2bf(v.z) | ((unsigned)f2bf(v.w) << 16)};
        const int lbyte = row * 256 + c4 * 8;
        *(uint2*)(AB + (lbyte ^ ((row & 7) << 4))) = pk;
    }
    for (int p = tid; p < 1024; p += 256) {        // stage WB: l2t half0
        const int byte = p * 16; const int nl = byte >> 8;
        *(float4*)(WB + (byte ^ ((nl & 7) << 4))) = *(const float4*)((const char*)l2t + byte);
    }
    __syncthreads();

    const int lane = tid & 63, wv = tid >> 6, col0 = lane & 15, g4 = lane >> 4;
    const int m = wv * 16 + col0;
    float b1v[8], b2v[8];
#pragma unroll
    for (int f = 0; f < 8; f++) {
        const int colf = (f >> 2) * 64 + (f & 3) * 16 + col0;
        b1v[f] = lin2_b[colf];
        b2v[f] = lin_b[colf];
    }

    f32x4 acc[8] = {};
#pragma unroll
    for (int h = 0; h < 2; h++) {
        if (h == 1) {
            __syncthreads();
            for (int p = tid; p < 1024; p += 256) {
                const int byte = p * 16; const int nl = byte >> 8;
                *(float4*)(WB + (byte ^ ((nl & 7) << 4))) =
                    *(const float4*)((const char*)l2t + 16384 + byte);
            }
            __syncthreads();
        }
#pragma unroll
        for (int kk = 0; kk < 4; kk++) {
            const int abyte = m * 256 + kk * 64 + g4 * 16;
            const bf16x8 af = *(const bf16x8*)(AB + (abyte ^ ((m & 7) << 4)));
#pragma unroll
            for (int q = 0; q < 4; q++) {
                const int l = q * 16 + col0;
                const int bbyte = l * 256 + kk * 64 + g4 * 16;
                const bf16x8 bf_ = *(const bf16x8*)(WB + (bbyte ^ ((l & 7) << 4)));
                acc[h * 4 + q] = __builtin_amdgcn_mfma_f32_16x16x32_bf16(af, bf_, acc[h * 4 + q], 0, 0, 0);
            }
        }
    }
    __syncthreads();   // all GEMM1 reads done; AB may be overlaid by T1

    // T2 = ssp(acc + b1) -> T1 (bf16); stage WB: lwt half0 in parallel
#pragma unroll
    for (int f = 0; f < 8; f++) {
        const int colf = (f >> 2) * 64 + (f & 3) * 16 + col0;
#pragma unroll
        for (int rg = 0; rg < 4; rg++) {
            const int row = wv * 16 + g4 * 4 + rg;
            const float tv = sspf(acc[f][rg] + b1v[f]);
            const int lbyte = row * 256 + colf * 2;
            *(ushort_t*)(T1 + (lbyte ^ ((row & 7) << 4))) = f2bf(tv);
        }
    }
    for (int p = tid; p < 1024; p += 256) {
        const int byte = p * 16; const int nl = byte >> 8;
        *(float4*)(WB + (byte ^ ((nl & 7) << 4))) = *(const float4*)((const char*)lwt + byte);
    }
    __syncthreads();

    f32x4 acc2[8] = {};
#pragma unroll
    for (int h = 0; h < 2; h++) {
        if (h == 1) {
            __syncthreads();
            for (int p = tid; p < 1024; p += 256) {
                const int byte = p * 16; const int nl = byte >> 8;
                *(float4*)(WB + (byte ^ ((nl & 7) << 4))) =
                    *(const float4*)((const char*)lwt + 16384 + byte);
            }
            __syncthreads();
        }
#pragma unroll
        for (int kk = 0; kk < 4; kk++) {
            const int abyte = m * 256 + kk * 64 + g4 * 16;
            const bf16x8 af = *(const bf16x8*)(T1 + (abyte ^ ((m & 7) << 4)));
#pragma unroll
            for (int q = 0; q < 4; q++) {
                const int l = q * 16 + col0;
                const int bbyte = l * 256 + kk * 64 + g4 * 16;
                const bf16x8 bf_ = *(const bf16x8*)(WB + (bbyte ^ ((l & 7) << 4)));
                acc2[h * 4 + q] = __builtin_amdgcn_mfma_f32_16x16x32_bf16(af, bf_, acc2[h * 4 + q], 0, 0, 0);
            }
        }
    }
#pragma unroll
    for (int f = 0; f < 8; f++) {
        const int colf = (f >> 2) * 64 + (f & 3) * 16 + col0;
#pragma unroll
        for (int rg = 0; rg < 4; rg++) {
            const int row = wv * 16 + g4 * 4 + rg;
            out[(size_t)(n0 + row) * HH + colf] = acc2[f][rg] + b2v[f];
        }
    }
}

// ---------------------------------------------------------------------------
__global__ void k_copy_pos(const float* __restrict__ pos, float* __restrict__ out) {
    const int i = blockIdx.x * 256 + threadIdx.x;
    if (i < NN * 3) out[i] = pos[i];
}

// ---------------------------------------------------------------------------
extern "C" void kernel_launch(void* const* d_in, const int* in_sizes, int n_in,
                              void* d_out, int out_size, void* d_ws, size_t ws_size,
                              hipStream_t stream)
{
    const float* h       = (const float*)d_in[0];
    const float* pos     = (const float*)d_in[1];
    const int*   ei      = (const int*)d_in[2];
    const void*  maskp   = d_in[3];
    const float* attn_w1 = (const float*)d_in[4];
    const float* attn_b1 = (const float*)d_in[5];
    const float* attn_w2 = (const float*)d_in[6];
    const float* attn_b2 = (const float*)d_in[7];
    const float* filt_w1 = (const float*)d_in[8];
    const float* filt_b1 = (const float*)d_in[9];
    const float* filt_w2 = (const float*)d_in[10];
    const float* filt_b2 = (const float*)d_in[11];
    const float* lin1_w  = (const float*)d_in[12];
    const float* lin2_w  = (const float*)d_in[13];
    const float* lin2_b  = (const float*)d_in[14];
    const float* lin_w   = (const float*)d_in[15];
    const float* lin_b   = (const float*)d_in[16];

    char* p = (char*)d_ws;
    auto alloc = [&](size_t bytes) { char* r = p; p += (bytes + 255) & ~(size_t)255; return r; };

    ushort_t* ub    = (ushort_t*)alloc((size_t)NN * HH * 2);
    ushort_t* vb    = (ushort_t*)alloc((size_t)NN * HH * 2);
    ushort_t* xhb   = (ushort_t*)alloc((size_t)NN * HH * 2);
    float*    score = (float*)alloc((size_t)EE * 4);
    unsigned* menc  = (unsigned*)alloc((size_t)NN * 4);   // menc/ssum/count/mcount
    float*    ssum  = (float*)alloc((size_t)NN * 4);      // contiguous zero block
    int*      count = (int*)alloc((size_t)NN * 4);
    int*      mcount= (int*)alloc(4);
    int*      cursor= (int*)alloc((size_t)NN * 4);
    float*    agg   = (float*)alloc((size_t)NN * HH * 4);
    int*      flag  = (int*)alloc(4);
    uint2*    mrec  = (uint2*)alloc((size_t)EE * 8);
    uint4*    erec  = (uint4*)alloc((size_t)EE * 16);
    ushort_t* atab  = (ushort_t*)alloc((size_t)TBINS * HH * 2);
    ushort_t* btab  = (ushort_t*)alloc((size_t)TBINS * HH * 2);
    ushort_t* w2t   = (ushort_t*)alloc((size_t)128 * 128 * 2);
    ushort_t* wut   = (ushort_t*)alloc((size_t)128 * 128 * 2);
    ushort_t* wvt   = (ushort_t*)alloc((size_t)128 * 128 * 2);
    ushort_t* wxt   = (ushort_t*)alloc((size_t)128 * 128 * 2);
    ushort_t* l2t   = (ushort_t*)alloc((size_t)128 * 128 * 2);
    ushort_t* lwt   = (ushort_t*)alloc((size_t)128 * 128 * 2);

    float* out_h   = (float*)d_out;
    float* out_pos = out_h + (size_t)NN * HH;

    hipMemsetAsync(menc, 0, (size_t)3 * NN * 4 + 256, stream);  // menc+ssum+count+mcount

    k_detect<<<1, 256, 0, stream>>>((const unsigned char*)maskp, flag);
    k_prep_w<<<384, 256, 0, stream>>>(filt_w2, attn_w1, lin1_w, lin2_w, lin_w,
                                      w2t, wut, wvt, wxt, l2t, lwt);
    k_prep_tab<<<TBINS / 2, 256, 0, stream>>>(filt_w1, attn_w1, attn_b1, atab, btab);
    k_node_proj<<<dim3(NN / 64, 3), 256, 0, stream>>>(h, wut, wvt, wxt, ub, vb, xhb);
    k_compact<<<EE / CPB, 256, 0, stream>>>(ei, maskp, flag, count, mcount, mrec);
    k_edge_score<<<EE / 64, 256, 0, stream>>>(pos, mrec, mcount, ub, vb, btab,
                                              attn_w2, attn_b2, score, menc);
    k_ssum<<<EE / 256, 256, 0, stream>>>(mrec, mcount, score, menc, ssum);
    k_scan<<<1, 512, 0, stream>>>(count, cursor);
    k_scatter<<<EE / 256, 256, 0, stream>>>(ei, maskp, flag, pos, score, menc, ssum,
                                            cursor, erec);

    hipMemsetAsync(agg, 0, (size_t)NN * HH * sizeof(float), stream);
    k_filter_mfma<<<EE / 64, 256, 0, stream>>>(erec, atab, filt_b1, w2t, filt_b2, xhb, agg);

    k_final<<<NN / 64, 256, 0, stream>>>(agg, l2t, lin2_b, lwt, lin_b, out_h);
    k_copy_pos<<<(NN * 3 + 255) / 256, 256, 0, stream>>>(pos, out_pos);
}